// Round 8
// baseline (618.179 us; speedup 1.0000x reference)
//
#include <hip/hip_runtime.h>

#define NGRAPHS 256
#define DIM     256   // K (input dim)
#define HID     128   // N (hidden dim)
#define TILE    128   // rows per block

typedef __attribute__((ext_vector_type(8))) short bf16x8;
typedef __attribute__((ext_vector_type(4))) float f32x4;

__device__ __forceinline__ ushort f2bf_rne(float f) {
    unsigned u = __float_as_uint(f);
    unsigned r = u + 0x7fffu + ((u >> 16) & 1u);
    return (ushort)(r >> 16);
}
__device__ __forceinline__ float bf2f(ushort h) {
    return __uint_as_float(((unsigned)h) << 16);
}
__device__ __forceinline__ float tanh_fast(float x) {
    float e = __expf(2.0f * x);
    return 1.0f - 2.0f * __builtin_amdgcn_rcpf(1.0f + e);
}

// fire-and-forget global->LDS DMA, 16B per lane; lds ptr must be wave-uniform
__device__ __forceinline__ void glds16(const void* g, void* l) {
    __builtin_amdgcn_global_load_lds(
        (const __attribute__((address_space(1))) unsigned int*)g,
        (__attribute__((address_space(3))) unsigned int*)l, 16, 0, 0);
}

// split fp32 -> bf16 hi/lo in registers (hi = truncate, lo = truncate(f-hi))
__device__ __forceinline__ void cvt8(float4 v0, float4 v1, bf16x8& h, bf16x8& l) {
    float f[8] = {v0.x, v0.y, v0.z, v0.w, v1.x, v1.y, v1.z, v1.w};
    unsigned hu[8], lu[8];
#pragma unroll
    for (int i = 0; i < 8; ++i) {
        unsigned u = __float_as_uint(f[i]);
        unsigned hb = u & 0xffff0000u;
        hu[i] = u;
        lu[i] = __float_as_uint(f[i] - __uint_as_float(hb));
    }
    union { unsigned w[4]; bf16x8 v; } H, L;
#pragma unroll
    for (int j = 0; j < 4; ++j) {
        H.w[j] = (hu[2 * j] >> 16) | (hu[2 * j + 1] & 0xffff0000u);
        L.w[j] = (lu[2 * j] >> 16) | (lu[2 * j + 1] & 0xffff0000u);
    }
    h = H.v; l = L.v;
}

// ---------------------------------------------------------------------------
// Prep: w1 [256(k)][128(n)] fp32 -> fragment-major bf16 hi/lo
// ---------------------------------------------------------------------------
__global__ void k_prep(const float* __restrict__ w1, ushort* __restrict__ w1f)
{
    int idx = blockIdx.x * 256 + threadIdx.x;   // 0..32767, k-major
    int k  = idx >> 7, nn = idx & 127;
    int ks = k >> 5, lhi = (k >> 3) & 3, j = k & 7;
    int nf = nn >> 4, llo = nn & 15;
    int lane = lhi * 16 + llo;
    float v = w1[idx];
    ushort hb = f2bf_rne(v);
    ushort lb = f2bf_rne(v - bf2f(hb));
    int base = (ks * 8 + nf) * 1024 + lane * 8 + j;
    w1f[base]       = hb;
    w1f[base + 512] = lb;
}

// ---------------------------------------------------------------------------
// Main (UNCHANGED from round 7): dbuf glds16 + counted vmcnt + raw barriers.
// ---------------------------------------------------------------------------
__global__ __launch_bounds__(256, 2) void k_scores(
    const float* __restrict__ x, const int* __restrict__ batch,
    const ushort* __restrict__ w1f,
    const float* __restrict__ b1, const float* __restrict__ w2,
    const float* __restrict__ b2,
    float* __restrict__ wsp, float* __restrict__ wse, int* __restrict__ wsid,
    int n)
{
    __shared__ __align__(16) unsigned char smem[65536];
    float  (*xs)[TILE * 32] = (float(*)[TILE * 32])smem;             // 2 x 16 KB
    ushort (*bs)[8 * 1024]  = (ushort(*)[8 * 1024])(smem + 32768);   // 2 x 16 KB
    float  (*sred)[2][DIM]  = (float(*)[2][DIM])smem;                // alias, 8 KB
    __shared__ float evals[TILE];
    __shared__ int   gid[TILE];
    __shared__ float ep[4];

    const int t    = threadIdx.x;
    const int b    = blockIdx.x;
    const int r0   = b * TILE;
    const int wid  = t >> 6;
    const int lane = t & 63;
    const int lhi  = lane >> 4;
    const int llo  = lane & 15;

    if (t < TILE) {
        int r = r0 + t;
        gid[t] = batch[r < n ? r : (n - 1)];
    }

    size_t xoff[4], boff[4];
    int    xl[4], bl[4];
#pragma unroll
    for (int i = 0; i < 4; ++i) {
        int p = i * 256 + t;
        int r = p >> 3, s = p & 7;
        int q = s ^ (r & 7);
        int rsrc = r0 + r; if (rsrc >= n) rsrc = n - 1;
        xoff[i] = (size_t)rsrc * DIM + q * 4;
        boff[i] = (size_t)p * 8;
        xl[i]   = (i * 256 + wid * 64) * 4;
        bl[i]   = (i * 256 + wid * 64) * 8;
    }

#define STAGE(sel, KS) do {                                          \
    _Pragma("unroll")                                                \
    for (int i = 0; i < 4; ++i) {                                    \
        glds16(x + xoff[i] + (KS) * 32, &xs[sel][xl[i]]);            \
        glds16(w1f + (size_t)(KS) * 8192 + boff[i], &bs[sel][bl[i]]);\
    }                                                                \
} while (0)

    f32x4 acc[2][8];
#pragma unroll
    for (int i = 0; i < 2; ++i)
#pragma unroll
        for (int j = 0; j < 8; ++j) acc[i][j] = (f32x4){0.f, 0.f, 0.f, 0.f};

    const int ra0 = wid * 32 + llo;
    const int ra1 = ra0 + 16;
    const int rb7 = ra0 & 7;
    const int c00 = (ra0 * 8 + ((2 * lhi)     ^ rb7)) * 4;
    const int c01 = (ra0 * 8 + ((2 * lhi + 1) ^ rb7)) * 4;
    const int c10 = (ra1 * 8 + ((2 * lhi)     ^ rb7)) * 4;
    const int c11 = (ra1 * 8 + ((2 * lhi + 1) ^ rb7)) * 4;

    STAGE(0, 0);
#pragma unroll
    for (int ks = 0; ks < 8; ++ks) {
        const int cur = ks & 1;
        if (ks < 7) {
            STAGE(cur ^ 1, ks + 1);
            asm volatile("s_waitcnt vmcnt(8)" ::: "memory");
        } else {
            asm volatile("s_waitcnt vmcnt(0)" ::: "memory");
        }
        __builtin_amdgcn_sched_barrier(0);
        __builtin_amdgcn_s_barrier();
        __builtin_amdgcn_sched_barrier(0);

        float4 a0 = *(const float4*)&xs[cur][c00];
        float4 a1 = *(const float4*)&xs[cur][c01];
        float4 c0 = *(const float4*)&xs[cur][c10];
        float4 c1 = *(const float4*)&xs[cur][c11];
        bf16x8 ah0, al0, ah1, al1;
        cvt8(a0, a1, ah0, al0);
        cvt8(c0, c1, ah1, al1);

#pragma unroll
        for (int nf = 0; nf < 8; ++nf) {
            bf16x8 bh = *(const bf16x8*)&bs[cur][(nf * 2 + 0) * 512 + lane * 8];
            bf16x8 bl16 = *(const bf16x8*)&bs[cur][(nf * 2 + 1) * 512 + lane * 8];
            acc[0][nf] = __builtin_amdgcn_mfma_f32_16x16x32_bf16(ah0, bh,   acc[0][nf], 0, 0, 0);
            acc[1][nf] = __builtin_amdgcn_mfma_f32_16x16x32_bf16(ah1, bh,   acc[1][nf], 0, 0, 0);
            acc[0][nf] = __builtin_amdgcn_mfma_f32_16x16x32_bf16(ah0, bl16, acc[0][nf], 0, 0, 0);
            acc[1][nf] = __builtin_amdgcn_mfma_f32_16x16x32_bf16(ah1, bl16, acc[1][nf], 0, 0, 0);
            acc[0][nf] = __builtin_amdgcn_mfma_f32_16x16x32_bf16(al0, bh,   acc[0][nf], 0, 0, 0);
            acc[1][nf] = __builtin_amdgcn_mfma_f32_16x16x32_bf16(al1, bh,   acc[1][nf], 0, 0, 0);
        }
        __builtin_amdgcn_sched_barrier(0);
        __builtin_amdgcn_s_barrier();
        __builtin_amdgcn_sched_barrier(0);
    }
#undef STAGE

    float b2v = b2[0];
    float b1v[8], w2v[8];
#pragma unroll
    for (int nf = 0; nf < 8; ++nf) {
        b1v[nf] = b1[nf * 16 + llo];
        w2v[nf] = w2[nf * 16 + llo];
    }
    float sc[8];
#pragma unroll
    for (int mf = 0; mf < 2; ++mf)
#pragma unroll
        for (int rg = 0; rg < 4; ++rg) {
            float p = 0.f;
#pragma unroll
            for (int nf = 0; nf < 8; ++nf)
                p += tanh_fast(acc[mf][nf][rg] + b1v[nf]) * w2v[nf];
            sc[mf * 4 + rg] = p;
        }
#pragma unroll
    for (int off = 1; off < 16; off <<= 1)
#pragma unroll
        for (int q = 0; q < 8; ++q) sc[q] += __shfl_xor(sc[q], off, 64);

    if (llo == 0) {
#pragma unroll
        for (int mf = 0; mf < 2; ++mf)
#pragma unroll
            for (int rg = 0; rg < 4; ++rg) {
                int row = wid * 32 + mf * 16 + lhi * 4 + rg;
                float s = sc[mf * 4 + rg] + b2v;
                evals[row] = (r0 + row < n) ? __expf(s) : 0.f;
            }
    }
    __syncthreads();

    {
        const int g0 = gid[0];
        float4 a0 = {0.f, 0.f, 0.f, 0.f}, a1 = {0.f, 0.f, 0.f, 0.f};
        for (int bt = 0; bt < 4; ++bt) {
            float4 xv[8];
#pragma unroll
            for (int j = 0; j < 8; ++j) {
                int rsrc = r0 + wid * 32 + bt * 8 + j;
                if (rsrc >= n) rsrc = n - 1;
                xv[j] = *(const float4*)(x + (size_t)rsrc * DIM + lane * 4);
            }
#pragma unroll
            for (int j = 0; j < 8; ++j) {
                int row = wid * 32 + bt * 8 + j;
                float e = evals[row];
                if (gid[row] != g0) {
                    a1.x = fmaf(e, xv[j].x, a1.x); a1.y = fmaf(e, xv[j].y, a1.y);
                    a1.z = fmaf(e, xv[j].z, a1.z); a1.w = fmaf(e, xv[j].w, a1.w);
                } else {
                    a0.x = fmaf(e, xv[j].x, a0.x); a0.y = fmaf(e, xv[j].y, a0.y);
                    a0.z = fmaf(e, xv[j].z, a0.z); a0.w = fmaf(e, xv[j].w, a0.w);
                }
            }
        }
        *(float4*)&sred[wid][0][lane * 4] = a0;
        *(float4*)&sred[wid][1][lane * 4] = a1;
    }
    __syncthreads();
    {
        float s0 = sred[0][0][t] + sred[1][0][t] + sred[2][0][t] + sred[3][0][t];
        float s1 = sred[0][1][t] + sred[1][1][t] + sred[2][1][t] + sred[3][1][t];
        wsp[(size_t)b * 512 + t]       = s0;
        wsp[(size_t)b * 512 + 256 + t] = s1;
        if (t == 0) wsid[b] = gid[0];
    }

    float rsum = (t < TILE) ? evals[t] : 0.f;
#pragma unroll
    for (int off = 32; off; off >>= 1) rsum += __shfl_down(rsum, off, 64);
    if ((t & 63) == 0) ep[t >> 6] = rsum;
    __syncthreads();
    if (t == 0) wse[b] = ep[0] + ep[1];
}

// ---------------------------------------------------------------------------
// ABLATION 1: staging-only. Exact R7 staging loop (glds16 + counted vmcnt +
// raw barriers), zero compute, repeated 8x. Writes only to junk.
// ---------------------------------------------------------------------------
__global__ __launch_bounds__(256, 2) void k_ab_stage(
    const float* __restrict__ x, const ushort* __restrict__ w1f,
    float* __restrict__ junk, int n)
{
    __shared__ __align__(16) unsigned char smem[65536];
    float  (*xs)[TILE * 32] = (float(*)[TILE * 32])smem;
    ushort (*bs)[8 * 1024]  = (ushort(*)[8 * 1024])(smem + 32768);

    const int t   = threadIdx.x;
    const int b   = blockIdx.x;
    const int r0  = b * TILE;
    const int wid = t >> 6;

    size_t xoff[4], boff[4];
    int    xl[4], bl[4];
#pragma unroll
    for (int i = 0; i < 4; ++i) {
        int p = i * 256 + t;
        int r = p >> 3, s = p & 7;
        int q = s ^ (r & 7);
        int rsrc = r0 + r; if (rsrc >= n) rsrc = n - 1;
        xoff[i] = (size_t)rsrc * DIM + q * 4;
        boff[i] = (size_t)p * 8;
        xl[i]   = (i * 256 + wid * 64) * 4;
        bl[i]   = (i * 256 + wid * 64) * 8;
    }

#define STG(sel, KS) do {                                            \
    _Pragma("unroll")                                                \
    for (int i = 0; i < 4; ++i) {                                    \
        glds16(x + xoff[i] + (KS) * 32, &xs[sel][xl[i]]);            \
        glds16(w1f + (size_t)(KS) * 8192 + boff[i], &bs[sel][bl[i]]);\
    }                                                                \
} while (0)

    for (int rep = 0; rep < 8; ++rep) {
        STG(0, 0);
#pragma unroll
        for (int ks = 0; ks < 8; ++ks) {
            const int cur = ks & 1;
            if (ks < 7) {
                STG(cur ^ 1, ks + 1);
                asm volatile("s_waitcnt vmcnt(8)" ::: "memory");
            } else {
                asm volatile("s_waitcnt vmcnt(0)" ::: "memory");
            }
            __builtin_amdgcn_sched_barrier(0);
            __builtin_amdgcn_s_barrier();
            __builtin_amdgcn_sched_barrier(0);
            // (no compute)
            __builtin_amdgcn_sched_barrier(0);
            __builtin_amdgcn_s_barrier();
            __builtin_amdgcn_sched_barrier(0);
        }
    }
#undef STG
    if (t == 0) junk[b] = xs[0][0] + (float)bs[0][0];
}

// ---------------------------------------------------------------------------
// ABLATION 2: compute-only. Stage both buffers once, then 6 reps of the full
// {ds_read+cvt+MFMA k-loop + epilogue + phase B}. No staging in the loop.
// Writes only to junk regions.
// ---------------------------------------------------------------------------
__global__ __launch_bounds__(256, 2) void k_ab_rest(
    const float* __restrict__ x, const int* __restrict__ batch,
    const ushort* __restrict__ w1f,
    const float* __restrict__ b1, const float* __restrict__ w2,
    const float* __restrict__ b2,
    float* __restrict__ junkp, float* __restrict__ junke, int n)
{
    __shared__ __align__(16) unsigned char smem[65536];
    float  (*xs)[TILE * 32] = (float(*)[TILE * 32])smem;
    ushort (*bs)[8 * 1024]  = (ushort(*)[8 * 1024])(smem + 32768);
    float  (*sred)[2][DIM]  = (float(*)[2][DIM])(smem + 32768);  // alias over bs (post-loop)
    __shared__ float evals[TILE];
    __shared__ int   gid[TILE];
    __shared__ float ep[4];

    const int t    = threadIdx.x;
    const int b    = blockIdx.x;
    const int r0   = b * TILE;
    const int wid  = t >> 6;
    const int lane = t & 63;
    const int lhi  = lane >> 4;
    const int llo  = lane & 15;

    if (t < TILE) {
        int r = r0 + t;
        gid[t] = batch[r < n ? r : (n - 1)];
    }

    size_t xoff[4], boff[4];
    int    xl[4], bl[4];
#pragma unroll
    for (int i = 0; i < 4; ++i) {
        int p = i * 256 + t;
        int r = p >> 3, s = p & 7;
        int q = s ^ (r & 7);
        int rsrc = r0 + r; if (rsrc >= n) rsrc = n - 1;
        xoff[i] = (size_t)rsrc * DIM + q * 4;
        boff[i] = (size_t)p * 8;
        xl[i]   = (i * 256 + wid * 64) * 4;
        bl[i]   = (i * 256 + wid * 64) * 8;
    }
    // stage BOTH buffers once (real data), then never again
#pragma unroll
    for (int sel = 0; sel < 2; ++sel)
#pragma unroll
        for (int i = 0; i < 4; ++i) {
            glds16(x + xoff[i] + sel * 32, &xs[sel][xl[i]]);
            glds16(w1f + (size_t)sel * 8192 + boff[i], &bs[sel][bl[i]]);
        }
    __syncthreads();

    const int ra0 = wid * 32 + llo;
    const int ra1 = ra0 + 16;
    const int rb7 = ra0 & 7;
    const int c00 = (ra0 * 8 + ((2 * lhi)     ^ rb7)) * 4;
    const int c01 = (ra0 * 8 + ((2 * lhi + 1) ^ rb7)) * 4;
    const int c10 = (ra1 * 8 + ((2 * lhi)     ^ rb7)) * 4;
    const int c11 = (ra1 * 8 + ((2 * lhi + 1) ^ rb7)) * 4;

    float b2v = b2[0];
    float b1v[8], w2v[8];
#pragma unroll
    for (int nf = 0; nf < 8; ++nf) {
        b1v[nf] = b1[nf * 16 + llo];
        w2v[nf] = w2[nf * 16 + llo];
    }

    for (int rep = 0; rep < 6; ++rep) {
        f32x4 acc[2][8];
#pragma unroll
        for (int i = 0; i < 2; ++i)
#pragma unroll
            for (int j = 0; j < 8; ++j) acc[i][j] = (f32x4){0.f, 0.f, 0.f, 0.f};

#pragma unroll
        for (int ks = 0; ks < 8; ++ks) {
            const int cur = ks & 1;
            __builtin_amdgcn_sched_barrier(0);
            __builtin_amdgcn_s_barrier();
            __builtin_amdgcn_sched_barrier(0);

            float4 a0 = *(const float4*)&xs[cur][c00];
            float4 a1 = *(const float4*)&xs[cur][c01];
            float4 c0 = *(const float4*)&xs[cur][c10];
            float4 c1 = *(const float4*)&xs[cur][c11];
            bf16x8 ah0, al0, ah1, al1;
            cvt8(a0, a1, ah0, al0);
            cvt8(c0, c1, ah1, al1);

#pragma unroll
            for (int nf = 0; nf < 8; ++nf) {
                bf16x8 bh = *(const bf16x8*)&bs[cur][(nf * 2 + 0) * 512 + lane * 8];
                bf16x8 bl16 = *(const bf16x8*)&bs[cur][(nf * 2 + 1) * 512 + lane * 8];
                acc[0][nf] = __builtin_amdgcn_mfma_f32_16x16x32_bf16(ah0, bh,   acc[0][nf], 0, 0, 0);
                acc[1][nf] = __builtin_amdgcn_mfma_f32_16x16x32_bf16(ah1, bh,   acc[1][nf], 0, 0, 0);
                acc[0][nf] = __builtin_amdgcn_mfma_f32_16x16x32_bf16(ah0, bl16, acc[0][nf], 0, 0, 0);
                acc[1][nf] = __builtin_amdgcn_mfma_f32_16x16x32_bf16(ah1, bl16, acc[1][nf], 0, 0, 0);
                acc[0][nf] = __builtin_amdgcn_mfma_f32_16x16x32_bf16(al0, bh,   acc[0][nf], 0, 0, 0);
                acc[1][nf] = __builtin_amdgcn_mfma_f32_16x16x32_bf16(al1, bh,   acc[1][nf], 0, 0, 0);
            }
            __builtin_amdgcn_sched_barrier(0);
            __builtin_amdgcn_s_barrier();
            __builtin_amdgcn_sched_barrier(0);
        }

        // epilogue (same as real)
        float sc[8];
#pragma unroll
        for (int mf = 0; mf < 2; ++mf)
#pragma unroll
            for (int rg = 0; rg < 4; ++rg) {
                float p = 0.f;
#pragma unroll
                for (int nf = 0; nf < 8; ++nf)
                    p += tanh_fast(acc[mf][nf][rg] + b1v[nf]) * w2v[nf];
                sc[mf * 4 + rg] = p;
            }
#pragma unroll
        for (int off = 1; off < 16; off <<= 1)
#pragma unroll
            for (int q = 0; q < 8; ++q) sc[q] += __shfl_xor(sc[q], off, 64);

        if (llo == 0) {
#pragma unroll
            for (int mf = 0; mf < 2; ++mf)
#pragma unroll
                for (int rg = 0; rg < 4; ++rg) {
                    int row = wid * 32 + mf * 16 + lhi * 4 + rg;
                    float s = sc[mf * 4 + rg] + b2v;
                    evals[row] = (r0 + row < n) ? __expf(s) : 0.f;
                }
        }
        __syncthreads();

        // phase B (same as real; x loads real addresses)
        {
            const int g0 = gid[0];
            float4 a0 = {0.f, 0.f, 0.f, 0.f}, a1 = {0.f, 0.f, 0.f, 0.f};
            for (int bt = 0; bt < 4; ++bt) {
                float4 xv[8];
#pragma unroll
                for (int j = 0; j < 8; ++j) {
                    int rsrc = r0 + wid * 32 + bt * 8 + j;
                    if (rsrc >= n) rsrc = n - 1;
                    xv[j] = *(const float4*)(x + (size_t)rsrc * DIM + lane * 4);
                }
#pragma unroll
                for (int j = 0; j < 8; ++j) {
                    int row = wid * 32 + bt * 8 + j;
                    float e = evals[row];
                    if (gid[row] != g0) {
                        a1.x = fmaf(e, xv[j].x, a1.x); a1.y = fmaf(e, xv[j].y, a1.y);
                        a1.z = fmaf(e, xv[j].z, a1.z); a1.w = fmaf(e, xv[j].w, a1.w);
                    } else {
                        a0.x = fmaf(e, xv[j].x, a0.x); a0.y = fmaf(e, xv[j].y, a0.y);
                        a0.z = fmaf(e, xv[j].z, a0.z); a0.w = fmaf(e, xv[j].w, a0.w);
                    }
                }
            }
            *(float4*)&sred[wid][0][lane * 4] = a0;
            *(float4*)&sred[wid][1][lane * 4] = a1;
        }
        __syncthreads();
        {
            float s0 = sred[0][0][t] + sred[1][0][t] + sred[2][0][t] + sred[3][0][t];
            float s1 = sred[0][1][t] + sred[1][1][t] + sred[2][1][t] + sred[3][1][t];
            junkp[(size_t)b * 512 + t]       = s0;
            junkp[(size_t)b * 512 + 256 + t] = s1;
        }
        float rsum = (t < TILE) ? evals[t] : 0.f;
#pragma unroll
        for (int off = 32; off; off >>= 1) rsum += __shfl_down(rsum, off, 64);
        if ((t & 63) == 0) ep[t >> 6] = rsum;
        __syncthreads();
        if (t == 0) junke[b] = ep[0] + ep[1];
        __syncthreads();   // sred alias region stable before next rep's ds_reads
    }
}

// ---------------------------------------------------------------------------
// Combine: one block per graph (unchanged)
// ---------------------------------------------------------------------------
__global__ __launch_bounds__(256) void k_combine(
    const int* __restrict__ batch, const float* __restrict__ wsp,
    const float* __restrict__ wse, const int* __restrict__ wsid,
    float* __restrict__ out, int n, int nblk)
{
    __shared__ float sred[256];
    __shared__ int bounds[2];
    const int g = blockIdx.x;
    const int d = threadIdx.x;

    float p = 0.f;
    for (int i = d; i < nblk; i += 256) p += wse[i];
    sred[d] = p;
    __syncthreads();
    for (int s = 128; s; s >>= 1) {
        if (d < s) sred[d] += sred[d + s];
        __syncthreads();
    }
    const float S = sred[0];

    if (d < 2) {
        int v = g + d;
        int lo = 0, hi = n;
        while (lo < hi) { int mid = (lo + hi) >> 1; if (batch[mid] < v) lo = mid + 1; else hi = mid; }
        bounds[d] = lo;
    }
    __syncthreads();

    const int st = bounds[0], en = bounds[1];
    float acc = 0.f;
    if (st < en) {
        for (int bb = st >> 7; bb <= (en - 1) >> 7; ++bb) {
            int slot = (wsid[bb] == g) ? 0 : 1;
            acc += wsp[(size_t)bb * 512 + slot * 256 + d];
        }
    }
    out[g * 256 + d] = acc / S;
}

// ---------------------------------------------------------------------------
extern "C" void kernel_launch(void* const* d_in, const int* in_sizes, int n_in,
                              void* d_out, int out_size, void* d_ws, size_t ws_size,
                              hipStream_t stream)
{
    const float* x     = (const float*)d_in[0];
    const int*   batch = (const int*)d_in[1];
    const float* w1    = (const float*)d_in[2];
    const float* b1    = (const float*)d_in[3];
    const float* w2    = (const float*)d_in[4];
    const float* b2    = (const float*)d_in[5];
    float* out = (float*)d_out;

    const int n    = in_sizes[1];                 // 200000
    const int nblk = (n + TILE - 1) / TILE;       // 1563

    // ws layout: w1f fragment-major hi/lo (128KB) | wsp | wse | wsid
    ushort* w1f = (ushort*)d_ws;
    float*  wsp = (float*)((char*)d_ws + (size_t)DIM * HID * 2 * sizeof(ushort));
    float*  wse = wsp + (size_t)nblk * 512;
    int*    wsid = (int*)(wse + nblk);

    k_prep<<<dim3(DIM * HID / 256), dim3(256), 0, stream>>>(w1, w1f);
    k_scores<<<dim3(nblk), dim3(256), 0, stream>>>(x, batch, w1f,
                                                   b1, w2, b2, wsp, wse, wsid, n);
    k_combine<<<dim3(NGRAPHS), dim3(256), 0, stream>>>(batch, wsp, wse, wsid,
                                                       out, n, nblk);

    // ---- ablation clones (write only to far junk region of ws) ----
    if (ws_size >= (size_t)32 * 1024 * 1024) {
        char*  jbase = (char*)d_ws + ws_size / 2;
        float* junkp = (float*)jbase;                          // nblk*512 floats
        float* junke = junkp + (size_t)nblk * 512;             // nblk floats
        float* junks = junke + nblk;                           // nblk floats
        k_ab_stage<<<dim3(nblk), dim3(256), 0, stream>>>(x, w1f, junks, n);
        k_ab_rest<<<dim3(nblk), dim3(256), 0, stream>>>(x, batch, w1f, b1, w2, b2,
                                                        junkp, junke, n);
    }
}

// Round 9
// 88.585 us; speedup vs baseline: 6.9784x; 6.9784x over previous
//
#include <hip/hip_runtime.h>

#define NGRAPHS 256
#define DIM     256   // K (input dim)
#define HID     128   // N (hidden dim)
#define TILE    128   // rows per block

typedef __attribute__((ext_vector_type(8))) short bf16x8;
typedef __attribute__((ext_vector_type(4))) float f32x4;

__device__ __forceinline__ ushort f2bf_rne(float f) {
    unsigned u = __float_as_uint(f);
    unsigned r = u + 0x7fffu + ((u >> 16) & 1u);
    return (ushort)(r >> 16);
}
__device__ __forceinline__ float tanh_fast(float x) {
    float e = __expf(2.0f * x);
    return 1.0f - 2.0f * __builtin_amdgcn_rcpf(1.0f + e);
}

// fire-and-forget global->LDS DMA, 16B per lane; lds ptr must be wave-uniform
__device__ __forceinline__ void glds16(const void* g, void* l) {
    __builtin_amdgcn_global_load_lds(
        (const __attribute__((address_space(1))) unsigned int*)g,
        (__attribute__((address_space(3))) unsigned int*)l, 16, 0, 0);
}

// split fp32 -> bf16 hi/lo in registers; xh+xl represents x to ~2^-17
__device__ __forceinline__ void cvt8(float4 v0, float4 v1, bf16x8& h, bf16x8& l) {
    float f[8] = {v0.x, v0.y, v0.z, v0.w, v1.x, v1.y, v1.z, v1.w};
    unsigned hu[8], lu[8];
#pragma unroll
    for (int i = 0; i < 8; ++i) {
        unsigned u = __float_as_uint(f[i]);
        unsigned hb = u & 0xffff0000u;
        hu[i] = u;
        lu[i] = __float_as_uint(f[i] - __uint_as_float(hb));
    }
    union { unsigned w[4]; bf16x8 v; } H, L;
#pragma unroll
    for (int j = 0; j < 4; ++j) {
        H.w[j] = (hu[2 * j] >> 16) | (hu[2 * j + 1] & 0xffff0000u);
        L.w[j] = (lu[2 * j] >> 16) | (lu[2 * j + 1] & 0xffff0000u);
    }
    h = H.v; l = L.v;
}

// ---------------------------------------------------------------------------
// Prep: w1 [256(k)][128(n)] fp32 -> fragment-major bf16 RNE, HI PLANE ONLY:
//   w1f[(ks*8+nf)*512 + lane*8 + j], lane = lhi*16+llo,
//   element = w1[ks*32+lhi*8+j][nf*16+llo]     (64 KB total)
// ---------------------------------------------------------------------------
__global__ void k_prep(const float* __restrict__ w1, ushort* __restrict__ w1f)
{
    int idx = blockIdx.x * 256 + threadIdx.x;   // 0..32767, k-major
    int k  = idx >> 7, nn = idx & 127;
    int ks = k >> 5, lhi = (k >> 3) & 3, j = k & 7;
    int nf = nn >> 4, llo = nn & 15;
    int lane = lhi * 16 + llo;
    w1f[(ks * 8 + nf) * 512 + lane * 8 + j] = f2bf_rne(w1[idx]);
}

// ---------------------------------------------------------------------------
// Main: 2-pass split-bf16 GEMM ((xh+xl)*wh), tri-buffered glds16 staging,
// counted vmcnt, ONE barrier per k-step. Then tanh -> @w2 -> exp ->
// per-graph weighted partials + block exp-sum. Deterministic.
// ---------------------------------------------------------------------------
__global__ __launch_bounds__(256, 2) void k_scores(
    const float* __restrict__ x, const int* __restrict__ batch,
    const ushort* __restrict__ w1f,
    const float* __restrict__ b1, const float* __restrict__ w2,
    const float* __restrict__ b2,
    float* __restrict__ wsp, float* __restrict__ wse, int* __restrict__ wsid,
    int n)
{
    // 3 x 24 KB buffers: x fp32 16 KB at +0, B bf16 8 KB at +16384.
    // Dead after the GEMM loop -> first 8 KB re-used as phase-B reduce buffer.
    __shared__ __align__(16) unsigned char smem[3 * 24576];
    __shared__ float evals[TILE];
    __shared__ int   gid[TILE];
    __shared__ float ep[4];
    float (*sred)[2][DIM] = (float(*)[2][DIM])smem;   // alias, 8 KB

    const int t    = threadIdx.x;
    const int b    = blockIdx.x;
    const int r0   = b * TILE;
    const int wid  = t >> 6;
    const int lane = t & 63;
    const int lhi  = lane >> 4;
    const int llo  = lane & 15;

    if (t < TILE) {
        int r = r0 + t;
        gid[t] = batch[r < n ? r : (n - 1)];
    }

    // staging addresses: x 16B-chunk XOR swizzle on the SOURCE side (linear
    // LDS dest); B linear both sides. All LDS dests wave-uniform.
    size_t xoff[4];
    int    xl[4];
#pragma unroll
    for (int i = 0; i < 4; ++i) {
        int p = i * 256 + t;            // 16B-chunk index 0..1023
        int r = p >> 3, s = p & 7;
        int q = s ^ (r & 7);
        int rsrc = r0 + r; if (rsrc >= n) rsrc = n - 1;
        xoff[i] = (size_t)rsrc * DIM + q * 4;
        xl[i]   = (i * 256 + wid * 64) * 16;   // byte offset, wave-uniform
    }
    size_t boff[2];
    int    bl[2];
#pragma unroll
    for (int i = 0; i < 2; ++i) {
        boff[i] = (size_t)(i * 256 + t) * 8;            // ushort offset
        bl[i]   = (i * 256 + wid * 64) * 16;            // byte offset
    }

#define XBUF(sel) ((float*)(smem + (sel) * 24576))
#define BBUF(sel) ((ushort*)(smem + (sel) * 24576 + 16384))
#define STAGE(sel, KS) do {                                              \
    _Pragma("unroll")                                                    \
    for (int i = 0; i < 4; ++i)                                          \
        glds16(x + xoff[i] + (KS) * 32, smem + (sel) * 24576 + xl[i]);   \
    _Pragma("unroll")                                                    \
    for (int i = 0; i < 2; ++i)                                          \
        glds16(w1f + (size_t)(KS) * 4096 + boff[i],                      \
               smem + (sel) * 24576 + 16384 + bl[i]);                    \
} while (0)

    f32x4 acc[2][8];
#pragma unroll
    for (int i = 0; i < 2; ++i)
#pragma unroll
        for (int j = 0; j < 8; ++j) acc[i][j] = (f32x4){0.f, 0.f, 0.f, 0.f};

    // A-fragment LDS chunk addresses (block-relative rows ra0, ra0+16)
    const int ra0 = wid * 32 + llo;
    const int ra1 = ra0 + 16;               // (ra1 & 7) == (ra0 & 7)
    const int rb7 = ra0 & 7;
    const int c00 = (ra0 * 8 + ((2 * lhi)     ^ rb7)) * 4;
    const int c01 = (ra0 * 8 + ((2 * lhi + 1) ^ rb7)) * 4;
    const int c10 = (ra1 * 8 + ((2 * lhi)     ^ rb7)) * 4;
    const int c11 = (ra1 * 8 + ((2 * lhi + 1) ^ rb7)) * 4;

    // ---- tri-buffered K-loop: one barrier per step, counted vmcnt ----
    STAGE(0, 0);
    STAGE(1, 1);
#pragma unroll
    for (int ks = 0; ks < 8; ++ks) {
        const int cur = ks % 3;
        if (ks < 7) {
            asm volatile("s_waitcnt vmcnt(6)" ::: "memory");  // stage(ks) done
        } else {
            asm volatile("s_waitcnt vmcnt(0)" ::: "memory");
        }
        __builtin_amdgcn_sched_barrier(0);
        __builtin_amdgcn_s_barrier();     // all waves: stage(ks) ready AND
                                          // everyone done reading buf (ks-1)%3
        __builtin_amdgcn_sched_barrier(0);
        if (ks < 6) STAGE((ks + 2) % 3, ks + 2);   // overwrites buf (ks-1)%3

        const float*  xsc = XBUF(cur);
        const ushort* bsc = BBUF(cur);
        float4 a0 = *(const float4*)&xsc[c00];
        float4 a1 = *(const float4*)&xsc[c01];
        float4 c0 = *(const float4*)&xsc[c10];
        float4 c1 = *(const float4*)&xsc[c11];
        bf16x8 ah0, al0, ah1, al1;
        cvt8(a0, a1, ah0, al0);
        cvt8(c0, c1, ah1, al1);

#pragma unroll
        for (int nf = 0; nf < 8; ++nf) {
            bf16x8 bh = *(const bf16x8*)&bsc[nf * 512 + lane * 8];
            acc[0][nf] = __builtin_amdgcn_mfma_f32_16x16x32_bf16(ah0, bh, acc[0][nf], 0, 0, 0);
            acc[1][nf] = __builtin_amdgcn_mfma_f32_16x16x32_bf16(ah1, bh, acc[1][nf], 0, 0, 0);
            acc[0][nf] = __builtin_amdgcn_mfma_f32_16x16x32_bf16(al0, bh, acc[0][nf], 0, 0, 0);
            acc[1][nf] = __builtin_amdgcn_mfma_f32_16x16x32_bf16(al1, bh, acc[1][nf], 0, 0, 0);
        }
    }
#undef STAGE
#undef XBUF
#undef BBUF

    // ---- epilogue: tanh + dot(w2); C layout: col=llo+16nf, row=lhi*4+rg ----
    float b2v = b2[0];
    float b1v[8], w2v[8];
#pragma unroll
    for (int nf = 0; nf < 8; ++nf) {
        b1v[nf] = b1[nf * 16 + llo];
        w2v[nf] = w2[nf * 16 + llo];
    }
    float sc[8];
#pragma unroll
    for (int mf = 0; mf < 2; ++mf)
#pragma unroll
        for (int rg = 0; rg < 4; ++rg) {
            float p = 0.f;
#pragma unroll
            for (int nf = 0; nf < 8; ++nf)
                p += tanh_fast(acc[mf][nf][rg] + b1v[nf]) * w2v[nf];
            sc[mf * 4 + rg] = p;
        }
#pragma unroll
    for (int off = 1; off < 16; off <<= 1)
#pragma unroll
        for (int q = 0; q < 8; ++q) sc[q] += __shfl_xor(sc[q], off, 64);

    if (llo == 0) {
#pragma unroll
        for (int mf = 0; mf < 2; ++mf)
#pragma unroll
            for (int rg = 0; rg < 4; ++rg) {
                int row = wid * 32 + mf * 16 + lhi * 4 + rg;
                float s = sc[mf * 4 + rg] + b2v;
                evals[row] = (r0 + row < n) ? __expf(s) : 0.f;
            }
    }
    __syncthreads();   // evals visible; staging arena dead -> sred alias ok

    // ---- phase B: weighted per-graph column partials, 8-deep load batches ----
    {
        const int g0 = gid[0];
        float4 a0 = {0.f, 0.f, 0.f, 0.f}, a1 = {0.f, 0.f, 0.f, 0.f};
        for (int bt = 0; bt < 4; ++bt) {
            float4 xv[8];
#pragma unroll
            for (int j = 0; j < 8; ++j) {
                int rsrc = r0 + wid * 32 + bt * 8 + j;
                if (rsrc >= n) rsrc = n - 1;          // e==0 there anyway
                xv[j] = *(const float4*)(x + (size_t)rsrc * DIM + lane * 4);
            }
#pragma unroll
            for (int j = 0; j < 8; ++j) {
                int row = wid * 32 + bt * 8 + j;
                float e = evals[row];
                if (gid[row] != g0) {
                    a1.x = fmaf(e, xv[j].x, a1.x); a1.y = fmaf(e, xv[j].y, a1.y);
                    a1.z = fmaf(e, xv[j].z, a1.z); a1.w = fmaf(e, xv[j].w, a1.w);
                } else {
                    a0.x = fmaf(e, xv[j].x, a0.x); a0.y = fmaf(e, xv[j].y, a0.y);
                    a0.z = fmaf(e, xv[j].z, a0.z); a0.w = fmaf(e, xv[j].w, a0.w);
                }
            }
        }
        *(float4*)&sred[wid][0][lane * 4] = a0;
        *(float4*)&sred[wid][1][lane * 4] = a1;
    }
    __syncthreads();
    {
        float s0 = sred[0][0][t] + sred[1][0][t] + sred[2][0][t] + sred[3][0][t];
        float s1 = sred[0][1][t] + sred[1][1][t] + sred[2][1][t] + sred[3][1][t];
        wsp[(size_t)b * 512 + t]       = s0;
        wsp[(size_t)b * 512 + 256 + t] = s1;
        if (t == 0) wsid[b] = gid[0];
    }

    // ---- block exp-sum (deterministic) ----
    float rsum = (t < TILE) ? evals[t] : 0.f;
#pragma unroll
    for (int off = 32; off; off >>= 1) rsum += __shfl_down(rsum, off, 64);
    if ((t & 63) == 0) ep[t >> 6] = rsum;
    __syncthreads();
    if (t == 0) wse[b] = ep[0] + ep[1];
}

// ---------------------------------------------------------------------------
// Combine: one block per graph
// ---------------------------------------------------------------------------
__global__ __launch_bounds__(256) void k_combine(
    const int* __restrict__ batch, const float* __restrict__ wsp,
    const float* __restrict__ wse, const int* __restrict__ wsid,
    float* __restrict__ out, int n, int nblk)
{
    __shared__ float sred[256];
    __shared__ int bounds[2];
    const int g = blockIdx.x;
    const int d = threadIdx.x;

    float p = 0.f;
    for (int i = d; i < nblk; i += 256) p += wse[i];
    sred[d] = p;
    __syncthreads();
    for (int s = 128; s; s >>= 1) {
        if (d < s) sred[d] += sred[d + s];
        __syncthreads();
    }
    const float S = sred[0];

    if (d < 2) {
        int v = g + d;
        int lo = 0, hi = n;
        while (lo < hi) { int mid = (lo + hi) >> 1; if (batch[mid] < v) lo = mid + 1; else hi = mid; }
        bounds[d] = lo;
    }
    __syncthreads();

    const int st = bounds[0], en = bounds[1];
    float acc = 0.f;
    if (st < en) {
        for (int bb = st >> 7; bb <= (en - 1) >> 7; ++bb) {
            int slot = (wsid[bb] == g) ? 0 : 1;
            acc += wsp[(size_t)bb * 512 + slot * 256 + d];
        }
    }
    out[g * 256 + d] = acc / S;
}

// ---------------------------------------------------------------------------
extern "C" void kernel_launch(void* const* d_in, const int* in_sizes, int n_in,
                              void* d_out, int out_size, void* d_ws, size_t ws_size,
                              hipStream_t stream)
{
    const float* x     = (const float*)d_in[0];
    const int*   batch = (const int*)d_in[1];
    const float* w1    = (const float*)d_in[2];
    const float* b1    = (const float*)d_in[3];
    const float* w2    = (const float*)d_in[4];
    const float* b2    = (const float*)d_in[5];
    float* out = (float*)d_out;

    const int n    = in_sizes[1];                 // 200000
    const int nblk = (n + TILE - 1) / TILE;       // 1563

    // ws layout: w1f hi-only fragment-major (64KB) | wsp | wse | wsid
    ushort* w1f = (ushort*)d_ws;
    float*  wsp = (float*)((char*)d_ws + (size_t)DIM * HID * sizeof(ushort));
    float*  wse = wsp + (size_t)nblk * 512;
    int*    wsid = (int*)(wse + nblk);

    k_prep<<<dim3(DIM * HID / 256), dim3(256), 0, stream>>>(w1, w1f);
    k_scores<<<dim3(nblk), dim3(256), 0, stream>>>(x, batch, w1f,
                                                   b1, w2, b2, wsp, wse, wsid, n);
    k_combine<<<dim3(NGRAPHS), dim3(256), 0, stream>>>(batch, wsp, wse, wsid,
                                                       out, n, nblk);
}

// Round 10
// 87.215 us; speedup vs baseline: 7.0880x; 1.0157x over previous
//
#include <hip/hip_runtime.h>

#define NGRAPHS 256
#define DIM     256   // K (input dim)
#define HID     128   // N (hidden dim)
#define TILE    128   // rows per block

typedef __attribute__((ext_vector_type(8))) short bf16x8;
typedef __attribute__((ext_vector_type(4))) float f32x4;

__device__ __forceinline__ ushort f2bf_rne(float f) {
    unsigned u = __float_as_uint(f);
    unsigned r = u + 0x7fffu + ((u >> 16) & 1u);
    return (ushort)(r >> 16);
}
__device__ __forceinline__ float tanh_fast(float x) {
    float e = __expf(2.0f * x);
    return 1.0f - 2.0f * __builtin_amdgcn_rcpf(1.0f + e);
}
// pack two fp32 -> u32 holding 2 bf16 (RNE)
__device__ __forceinline__ unsigned pack2(float a, float b) {
    unsigned ua = __float_as_uint(a), ub = __float_as_uint(b);
    unsigned ra = ua + 0x7fffu + ((ua >> 16) & 1u);
    unsigned rb = ub + 0x7fffu + ((ub >> 16) & 1u);
    return (ra >> 16) | (rb & 0xffff0000u);
}
// fire-and-forget global->LDS DMA, 16B per lane; lds ptr must be wave-uniform
__device__ __forceinline__ void glds16(const void* g, void* l) {
    __builtin_amdgcn_global_load_lds(
        (const __attribute__((address_space(1))) unsigned int*)g,
        (__attribute__((address_space(3))) unsigned int*)l, 16, 0, 0);
}

// ---------------------------------------------------------------------------
// Prep: w1 [256(k)][128(n)] fp32 -> fragment-major bf16 RNE (hi plane only):
//   w1f[(ks*8+nf)*512 + lane*8 + j], lane = lhi*16+llo,
//   element = w1[ks*32+lhi*8+j][nf*16+llo]     (64 KB total)
// ---------------------------------------------------------------------------
__global__ void k_prep(const float* __restrict__ w1, ushort* __restrict__ w1f)
{
    int idx = blockIdx.x * 256 + threadIdx.x;   // 0..32767, k-major
    int k  = idx >> 7, nn = idx & 127;
    int ks = k >> 5, lhi = (k >> 3) & 3, j = k & 7;
    int nf = nn >> 4, llo = nn & 15;
    int lane = lhi * 16 + llo;
    w1f[(ks * 8 + nf) * 512 + lane * 8 + j] = f2bf_rne(w1[idx]);
}

// ---------------------------------------------------------------------------
// Main: single-pass bf16 MFMA GEMM. A: global->reg->cvt->LDS (bf16, 80B row
// stride, tri-buffered). B: glds16 (double-buffered). One barrier per k-step,
// counted vmcnt (never 0 mid-loop). Then tanh -> @w2 -> exp -> per-graph
// weighted partials + block exp-sum. Deterministic.
// ---------------------------------------------------------------------------
__global__ __launch_bounds__(256, 3) void k_scores(
    const float* __restrict__ x, const int* __restrict__ batch,
    const ushort* __restrict__ w1f,
    const float* __restrict__ b1, const float* __restrict__ w2,
    const float* __restrict__ b2,
    float* __restrict__ wsp, float* __restrict__ wse, int* __restrict__ wsid,
    int n)
{
    // arena: 3 x-bufs (128 rows x 80 B = 10240 B) + 2 B-bufs (8192 B) = 47104 B
    __shared__ __align__(16) unsigned char smem[47104];
    __shared__ float evals[TILE];
    __shared__ int   gid[TILE];
    __shared__ float ep[4];
    float (*sred)[2][DIM] = (float(*)[2][DIM])smem;   // alias (dead post-loop)

    const int t    = threadIdx.x;
    const int b    = blockIdx.x;
    const int r0   = b * TILE;
    const int wid  = t >> 6;
    const int lane = t & 63;
    const int lhi  = lane >> 4;
    const int llo  = lane & 15;

    if (t < TILE) {
        int r = r0 + t;
        gid[t] = batch[r < n ? r : (n - 1)];
    }

    // x staging: thread t -> row t>>1, half t&1 (16 floats = 4 float4)
    int xrow = r0 + (t >> 1); if (xrow >= n) xrow = n - 1;
    const float* xp = x + (size_t)xrow * DIM + (t & 1) * 16;
    const int    wb = (t >> 1) * 80 + (t & 1) * 32;   // LDS byte off in x-buf

    // B staging (glds16, wave-uniform dest)
    size_t boff[2]; int bl[2];
#pragma unroll
    for (int i = 0; i < 2; ++i) {
        boff[i] = (size_t)(i * 256 + t) * 8;
        bl[i]   = (i * 256 + wid * 64) * 16;
    }

#define XBUF(s3) (smem + (s3) * 10240)
#define BBUF(s2) (smem + 30720 + (s2) * 8192)
#define STAGE_B(s2, KS) do {                                         \
    glds16(w1f + (size_t)(KS) * 4096 + boff[0], BBUF(s2) + bl[0]);   \
    glds16(w1f + (size_t)(KS) * 4096 + boff[1], BBUF(s2) + bl[1]);   \
} while (0)
#define XLOAD(st, KS) do {                                           \
    xr[st][0] = *(const float4*)(xp + (KS) * 32);                    \
    xr[st][1] = *(const float4*)(xp + (KS) * 32 + 4);                \
    xr[st][2] = *(const float4*)(xp + (KS) * 32 + 8);                \
    xr[st][3] = *(const float4*)(xp + (KS) * 32 + 12);               \
} while (0)
#define CVT_WRITE(st, s3) do {                                       \
    uint4 w0, w1v;                                                   \
    w0.x  = pack2(xr[st][0].x, xr[st][0].y);                         \
    w0.y  = pack2(xr[st][0].z, xr[st][0].w);                         \
    w0.z  = pack2(xr[st][1].x, xr[st][1].y);                         \
    w0.w  = pack2(xr[st][1].z, xr[st][1].w);                         \
    w1v.x = pack2(xr[st][2].x, xr[st][2].y);                         \
    w1v.y = pack2(xr[st][2].z, xr[st][2].w);                         \
    w1v.z = pack2(xr[st][3].x, xr[st][3].y);                         \
    w1v.w = pack2(xr[st][3].z, xr[st][3].w);                         \
    *(uint4*)(XBUF(s3) + wb)      = w0;                              \
    *(uint4*)(XBUF(s3) + wb + 16) = w1v;                             \
} while (0)

    f32x4 acc[2][8];
#pragma unroll
    for (int i = 0; i < 2; ++i)
#pragma unroll
        for (int j = 0; j < 8; ++j) acc[i][j] = (f32x4){0.f, 0.f, 0.f, 0.f};

    // A-fragment read offsets (bf16 rows, 80 B stride: conflict-free)
    const int ra0    = wid * 32 + llo;
    const int ra1    = ra0 + 16;
    const int abase0 = ra0 * 80 + lhi * 16;
    const int abase1 = ra1 * 80 + lhi * 16;

    float4 xr[2][4];

    // ---- prologue: x(0), B(0), x(1); drain x(0); write buf0.x ----
    XLOAD(0, 0);
    __builtin_amdgcn_sched_barrier(0);
    STAGE_B(0, 0);
    __builtin_amdgcn_sched_barrier(0);
    XLOAD(1, 1);
    __builtin_amdgcn_sched_barrier(0);
    asm volatile("s_waitcnt vmcnt(6)" ::: "memory");   // x(0) done
    __builtin_amdgcn_sched_barrier(0);
    CVT_WRITE(0, 0);

#pragma unroll
    for (int ks = 0; ks < 8; ++ks) {
        // s1: own stage(ks) done (B via vmcnt, x-writes via lgkm) -> barrier
        if (ks < 7) asm volatile("s_waitcnt vmcnt(4) lgkmcnt(0)" ::: "memory");
        else        asm volatile("s_waitcnt vmcnt(0) lgkmcnt(0)" ::: "memory");
        __builtin_amdgcn_sched_barrier(0);
        __builtin_amdgcn_s_barrier();       // all waves: buf[ks] fully staged
        __builtin_amdgcn_sched_barrier(0);

        // s3: issue next B (1 ahead) and next-next x (2 ahead)
        if (ks + 1 < 8) { STAGE_B((ks + 1) & 1, ks + 1); __builtin_amdgcn_sched_barrier(0); }
        if (ks + 2 < 8) { XLOAD(ks & 1, ks + 2);         __builtin_amdgcn_sched_barrier(0); }

        // s4/s5: drain x(ks+1) regs, convert + write into buf[(ks+1)%3]
        if (ks + 1 < 8) {
            if (ks <= 5) asm volatile("s_waitcnt vmcnt(6)" ::: "memory");
            else         asm volatile("s_waitcnt vmcnt(2)" ::: "memory");
            __builtin_amdgcn_sched_barrier(0);
            CVT_WRITE((ks + 1) & 1, (ks + 1) % 3);
        }

        // s6: compute(ks): 2 A-reads + 8 B-reads + 16 MFMA, no cvt
        const unsigned char* xb = XBUF(ks % 3);
        const unsigned char* bb = BBUF(ks & 1);
        bf16x8 ah0 = *(const bf16x8*)(xb + abase0);
        bf16x8 ah1 = *(const bf16x8*)(xb + abase1);
#pragma unroll
        for (int nf = 0; nf < 8; ++nf) {
            bf16x8 bh = *(const bf16x8*)(bb + (nf * 512 + lane * 8) * 2);
            acc[0][nf] = __builtin_amdgcn_mfma_f32_16x16x32_bf16(ah0, bh, acc[0][nf], 0, 0, 0);
            acc[1][nf] = __builtin_amdgcn_mfma_f32_16x16x32_bf16(ah1, bh, acc[1][nf], 0, 0, 0);
        }
    }
#undef STAGE_B
#undef XLOAD
#undef CVT_WRITE
#undef XBUF
#undef BBUF

    // ---- epilogue: tanh + dot(w2); C layout: col=llo+16nf, row=lhi*4+rg ----
    float b2v = b2[0];
    float b1v[8], w2v[8];
#pragma unroll
    for (int nf = 0; nf < 8; ++nf) {
        b1v[nf] = b1[nf * 16 + llo];
        w2v[nf] = w2[nf * 16 + llo];
    }
    float sc[8];
#pragma unroll
    for (int mf = 0; mf < 2; ++mf)
#pragma unroll
        for (int rg = 0; rg < 4; ++rg) {
            float p = 0.f;
#pragma unroll
            for (int nf = 0; nf < 8; ++nf)
                p += tanh_fast(acc[mf][nf][rg] + b1v[nf]) * w2v[nf];
            sc[mf * 4 + rg] = p;
        }
#pragma unroll
    for (int off = 1; off < 16; off <<= 1)
#pragma unroll
        for (int q = 0; q < 8; ++q) sc[q] += __shfl_xor(sc[q], off, 64);

    if (llo == 0) {
#pragma unroll
        for (int mf = 0; mf < 2; ++mf)
#pragma unroll
            for (int rg = 0; rg < 4; ++rg) {
                int row = wid * 32 + mf * 16 + lhi * 4 + rg;
                float s = sc[mf * 4 + rg] + b2v;
                evals[row] = (r0 + row < n) ? __expf(s) : 0.f;
            }
    }
    __syncthreads();   // evals visible; staging arena dead -> sred alias ok

    // ---- phase B: weighted per-graph column partials, 8-deep load batches ----
    {
        const int g0 = gid[0];
        float4 a0 = {0.f, 0.f, 0.f, 0.f}, a1 = {0.f, 0.f, 0.f, 0.f};
        for (int bt = 0; bt < 4; ++bt) {
            float4 xv[8];
#pragma unroll
            for (int j = 0; j < 8; ++j) {
                int rsrc = r0 + wid * 32 + bt * 8 + j;
                if (rsrc >= n) rsrc = n - 1;          // e==0 there anyway
                xv[j] = *(const float4*)(x + (size_t)rsrc * DIM + lane * 4);
            }
#pragma unroll
            for (int j = 0; j < 8; ++j) {
                int row = wid * 32 + bt * 8 + j;
                float e = evals[row];
                if (gid[row] != g0) {
                    a1.x = fmaf(e, xv[j].x, a1.x); a1.y = fmaf(e, xv[j].y, a1.y);
                    a1.z = fmaf(e, xv[j].z, a1.z); a1.w = fmaf(e, xv[j].w, a1.w);
                } else {
                    a0.x = fmaf(e, xv[j].x, a0.x); a0.y = fmaf(e, xv[j].y, a0.y);
                    a0.z = fmaf(e, xv[j].z, a0.z); a0.w = fmaf(e, xv[j].w, a0.w);
                }
            }
        }
        *(float4*)&sred[wid][0][lane * 4] = a0;
        *(float4*)&sred[wid][1][lane * 4] = a1;
    }
    __syncthreads();
    {
        float s0 = sred[0][0][t] + sred[1][0][t] + sred[2][0][t] + sred[3][0][t];
        float s1 = sred[0][1][t] + sred[1][1][t] + sred[2][1][t] + sred[3][1][t];
        wsp[(size_t)b * 512 + t]       = s0;
        wsp[(size_t)b * 512 + 256 + t] = s1;
        if (t == 0) wsid[b] = gid[0];
    }

    // ---- block exp-sum (deterministic) ----
    float rsum = (t < TILE) ? evals[t] : 0.f;
#pragma unroll
    for (int off = 32; off; off >>= 1) rsum += __shfl_down(rsum, off, 64);
    if ((t & 63) == 0) ep[t >> 6] = rsum;
    __syncthreads();
    if (t == 0) wse[b] = ep[0] + ep[1];
}

// ---------------------------------------------------------------------------
// Combine: one block per graph
// ---------------------------------------------------------------------------
__global__ __launch_bounds__(256) void k_combine(
    const int* __restrict__ batch, const float* __restrict__ wsp,
    const float* __restrict__ wse, const int* __restrict__ wsid,
    float* __restrict__ out, int n, int nblk)
{
    __shared__ float sred[256];
    __shared__ int bounds[2];
    const int g = blockIdx.x;
    const int d = threadIdx.x;

    float p = 0.f;
    for (int i = d; i < nblk; i += 256) p += wse[i];
    sred[d] = p;
    __syncthreads();
    for (int s = 128; s; s >>= 1) {
        if (d < s) sred[d] += sred[d + s];
        __syncthreads();
    }
    const float S = sred[0];

    if (d < 2) {
        int v = g + d;
        int lo = 0, hi = n;
        while (lo < hi) { int mid = (lo + hi) >> 1; if (batch[mid] < v) lo = mid + 1; else hi = mid; }
        bounds[d] = lo;
    }
    __syncthreads();

    const int st = bounds[0], en = bounds[1];
    float acc = 0.f;
    if (st < en) {
        for (int bb = st >> 7; bb <= (en - 1) >> 7; ++bb) {
            int slot = (wsid[bb] == g) ? 0 : 1;
            acc += wsp[(size_t)bb * 512 + slot * 256 + d];
        }
    }
    out[g * 256 + d] = acc / S;
}

// ---------------------------------------------------------------------------
extern "C" void kernel_launch(void* const* d_in, const int* in_sizes, int n_in,
                              void* d_out, int out_size, void* d_ws, size_t ws_size,
                              hipStream_t stream)
{
    const float* x     = (const float*)d_in[0];
    const int*   batch = (const int*)d_in[1];
    const float* w1    = (const float*)d_in[2];
    const float* b1    = (const float*)d_in[3];
    const float* w2    = (const float*)d_in[4];
    const float* b2    = (const float*)d_in[5];
    float* out = (float*)d_out;

    const int n    = in_sizes[1];                 // 200000
    const int nblk = (n + TILE - 1) / TILE;       // 1563

    // ws layout: w1f hi-only fragment-major (64KB) | wsp | wse | wsid
    ushort* w1f = (ushort*)d_ws;
    float*  wsp = (float*)((char*)d_ws + (size_t)DIM * HID * sizeof(ushort));
    float*  wse = wsp + (size_t)nblk * 512;
    int*    wsid = (int*)(wse + nblk);

    k_prep<<<dim3(DIM * HID / 256), dim3(256), 0, stream>>>(w1, w1f);
    k_scores<<<dim3(nblk), dim3(256), 0, stream>>>(x, batch, w1f,
                                                   b1, w2, b2, wsp, wse, wsid, n);
    k_combine<<<dim3(NGRAPHS), dim3(256), 0, stream>>>(batch, wsp, wse, wsid,
                                                       out, n, nblk);
}

// Round 11
// 86.562 us; speedup vs baseline: 7.1414x; 1.0075x over previous
//
#include <hip/hip_runtime.h>

#define NGRAPHS 256
#define DIM     256   // K (input dim)
#define HID     128   // N (hidden dim)
#define TILE    128   // rows per block

typedef __attribute__((ext_vector_type(8))) short bf16x8;
typedef __attribute__((ext_vector_type(4))) float f32x4;

__device__ __forceinline__ ushort f2bf_rne(float f) {
    unsigned u = __float_as_uint(f);
    unsigned r = u + 0x7fffu + ((u >> 16) & 1u);
    return (ushort)(r >> 16);
}
__device__ __forceinline__ float tanh_fast(float x) {
    float e = __expf(2.0f * x);
    return 1.0f - 2.0f * __builtin_amdgcn_rcpf(1.0f + e);
}
// pack two fp32 -> u32 holding 2 bf16 (RNE), elem0 in low half
__device__ __forceinline__ unsigned pack2(float a, float b) {
    unsigned ua = __float_as_uint(a), ub = __float_as_uint(b);
    unsigned ra = ua + 0x7fffu + ((ua >> 16) & 1u);
    unsigned rb = ub + 0x7fffu + ((ub >> 16) & 1u);
    return (ra >> 16) | (rb & 0xffff0000u);
}

// ---------------------------------------------------------------------------
// Prep: w1 [256(k)][128(n)] fp32 -> fragment-major bf16 RNE:
//   w1f[(ks*8+nf)*512 + lane*8 + j], lane = lhi*16+llo,
//   element = w1[ks*32+lhi*8+j][nf*16+llo]     (64 KB total, L2-hot)
// ---------------------------------------------------------------------------
__global__ void k_prep(const float* __restrict__ w1, ushort* __restrict__ w1f)
{
    int idx = blockIdx.x * 256 + threadIdx.x;   // 0..32767, k-major
    int k  = idx >> 7, nn = idx & 127;
    int ks = k >> 5, lhi = (k >> 3) & 3, j = k & 7;
    int nf = nn >> 4, llo = nn & 15;
    int lane = lhi * 16 + llo;
    w1f[(ks * 8 + nf) * 512 + lane * 8 + j] = f2bf_rne(w1[idx]);
}

// ---------------------------------------------------------------------------
// Main: stage x tile ONCE as bf16 (64KB XOR-swizzled LDS). Barrier-free
// MFMA k-loop (A from LDS, B global->reg prefetched). Epilogue: tanh, @w2,
// exp. Phase B reads the SAME LDS tile (no global re-read). Deterministic.
// ---------------------------------------------------------------------------
__global__ __launch_bounds__(256, 2) void k_scores(
    const float* __restrict__ x, const int* __restrict__ batch,
    const ushort* __restrict__ w1f,
    const float* __restrict__ b1, const float* __restrict__ w2,
    const float* __restrict__ b2,
    float* __restrict__ wsp, float* __restrict__ wse, int* __restrict__ wsid,
    int n)
{
    // x tile, bf16, row stride 512 B, 16B chunks XOR-swizzled by row&7
    __shared__ __align__(16) unsigned char xs[TILE * 512];   // 64 KB
    __shared__ float evals[TILE];
    __shared__ int   gid[TILE];
    __shared__ int   rtrans_s;
    __shared__ float ep[4];

    const int t    = threadIdx.x;
    const int b    = blockIdx.x;
    const int r0   = b * TILE;
    const int wid  = t >> 6;
    const int lane = t & 63;
    const int lhi  = lane >> 4;
    const int llo  = lane & 15;

    if (t < TILE) {
        int r = r0 + t;
        gid[t] = batch[r < n ? r : (n - 1)];
    }
    if (t == 0) rtrans_s = TILE;
    __syncthreads();
    // <=1 graph boundary per 128-row tile (min graph size ~650 >> 128)
    if (t >= 1 && t < TILE && gid[t] != gid[0] && gid[t - 1] == gid[0])
        rtrans_s = t;

    // ---- stage x tile: each thread = half a row (128 floats), 2-deep ----
    const int rt = t >> 1, h = t & 1, rq = rt & 7;
    int xrow = r0 + rt; if (xrow >= n) xrow = n - 1;
    const float* xp = x + (size_t)xrow * DIM + h * 128;
    unsigned char* xwp = xs + rt * 512;

    float4 v0[8], v1[8];
#define XLOADC(arr, c) do {                                           \
    _Pragma("unroll")                                                 \
    for (int i = 0; i < 8; ++i)                                       \
        arr[i] = *(const float4*)(xp + (c) * 32 + i * 4);             \
} while (0)
#define XWRITEC(arr, c) do {                                          \
    _Pragma("unroll")                                                 \
    for (int w = 0; w < 4; ++w) {                                     \
        uint4 W;                                                      \
        W.x = pack2(arr[2*w].x,   arr[2*w].y);                        \
        W.y = pack2(arr[2*w].z,   arr[2*w].w);                        \
        W.z = pack2(arr[2*w+1].x, arr[2*w+1].y);                      \
        W.w = pack2(arr[2*w+1].z, arr[2*w+1].w);                      \
        *(uint4*)(xwp + (((h * 16 + (c) * 4 + w) ^ rq) << 4)) = W;    \
    }                                                                 \
} while (0)
    XLOADC(v0, 0);
    XLOADC(v1, 1);
    XWRITEC(v0, 0);
    XLOADC(v0, 2);
    XWRITEC(v1, 1);
    XLOADC(v1, 3);
    XWRITEC(v0, 2);
    XWRITEC(v1, 3);
#undef XLOADC
#undef XWRITEC
    __syncthreads();   // tile + gid + rtrans visible; xs immutable hereafter

    // ---- barrier-free k-loop: A from LDS, B global->reg (1-step prefetch) ----
    f32x4 acc[2][8];
#pragma unroll
    for (int i = 0; i < 2; ++i)
#pragma unroll
        for (int j = 0; j < 8; ++j) acc[i][j] = (f32x4){0.f, 0.f, 0.f, 0.f};

    const int ra0 = wid * 32 + llo;
    const int ra1 = ra0 + 16;                 // same &7 as ra0
    const int q0  = ra0 & 7;
#define AADDR(ra, KS) ((const bf16x8*)(xs + (ra) * 512 + (((((KS) * 4) + lhi) ^ q0) << 4)))
    const ushort* bp = w1f + lane * 8;

    bf16x8 aC0 = *AADDR(ra0, 0);
    bf16x8 aC1 = *AADDR(ra1, 0);
    bf16x8 bC[8], bN[8];
#pragma unroll
    for (int nf = 0; nf < 8; ++nf) bC[nf] = *(const bf16x8*)(bp + nf * 512);

    bf16x8 aN0, aN1;
#pragma unroll
    for (int ks = 0; ks < 8; ++ks) {
        if (ks < 7) {
            aN0 = *AADDR(ra0, ks + 1);
            aN1 = *AADDR(ra1, ks + 1);
#pragma unroll
            for (int nf = 0; nf < 8; ++nf)
                bN[nf] = *(const bf16x8*)(bp + (ks + 1) * 4096 + nf * 512);
        }
        __builtin_amdgcn_sched_barrier(0);   // issue prefetch before MFMAs
#pragma unroll
        for (int nf = 0; nf < 8; ++nf) {
            acc[0][nf] = __builtin_amdgcn_mfma_f32_16x16x32_bf16(aC0, bC[nf], acc[0][nf], 0, 0, 0);
            acc[1][nf] = __builtin_amdgcn_mfma_f32_16x16x32_bf16(aC1, bC[nf], acc[1][nf], 0, 0, 0);
        }
        __builtin_amdgcn_sched_barrier(0);
        if (ks < 7) {
            aC0 = aN0; aC1 = aN1;
#pragma unroll
            for (int nf = 0; nf < 8; ++nf) bC[nf] = bN[nf];
        }
    }
#undef AADDR

    // ---- epilogue: tanh + dot(w2); C layout: col=llo+16nf, row=lhi*4+rg ----
    float b2v = b2[0];
    float b1v[8], w2v[8];
#pragma unroll
    for (int nf = 0; nf < 8; ++nf) {
        b1v[nf] = b1[nf * 16 + llo];
        w2v[nf] = w2[nf * 16 + llo];
    }
    float sc[8];
#pragma unroll
    for (int mf = 0; mf < 2; ++mf)
#pragma unroll
        for (int rg = 0; rg < 4; ++rg) {
            float p = 0.f;
#pragma unroll
            for (int nf = 0; nf < 8; ++nf)
                p += tanh_fast(acc[mf][nf][rg] + b1v[nf]) * w2v[nf];
            sc[mf * 4 + rg] = p;
        }
#pragma unroll
    for (int off = 1; off < 16; off <<= 1)
#pragma unroll
        for (int q = 0; q < 8; ++q) sc[q] += __shfl_xor(sc[q], off, 64);

    if (llo == 0) {
#pragma unroll
        for (int mf = 0; mf < 2; ++mf)
#pragma unroll
            for (int rg = 0; rg < 4; ++rg) {
                int row = wid * 32 + mf * 16 + lhi * 4 + rg;
                float s = sc[mf * 4 + rg] + b2v;
                evals[row] = (r0 + row < n) ? __expf(s) : 0.f;
            }
    }
    __syncthreads();   // evals visible block-wide

    // ---- phase B: weighted per-graph column sums FROM LDS (thread = col t) ----
    {
        const int rtr  = rtrans_s;
        const int c    = t >> 3;            // 16B chunk of this column
        const int woff = (2 * t) & 15;      // byte offset within chunk
        float a0 = 0.f, a1 = 0.f;
#pragma unroll 8
        for (int r = 0; r < TILE; ++r) {
            float e = evals[r];
            ushort v = *(const ushort*)(xs + r * 512 + ((c ^ (r & 7)) << 4) + woff);
            float xv = __uint_as_float(((unsigned)v) << 16);
            if (r < rtr) a0 = fmaf(e, xv, a0);
            else         a1 = fmaf(e, xv, a1);
        }
        wsp[(size_t)b * 512 + t]       = a0;
        wsp[(size_t)b * 512 + 256 + t] = a1;
        if (t == 0) wsid[b] = gid[0];
    }

    // ---- block exp-sum (deterministic) ----
    float rsum = (t < TILE) ? evals[t] : 0.f;
#pragma unroll
    for (int off = 32; off; off >>= 1) rsum += __shfl_down(rsum, off, 64);
    if ((t & 63) == 0) ep[t >> 6] = rsum;
    __syncthreads();
    if (t == 0) wse[b] = ep[0] + ep[1];
}

// ---------------------------------------------------------------------------
// Combine: one block per graph
// ---------------------------------------------------------------------------
__global__ __launch_bounds__(256) void k_combine(
    const int* __restrict__ batch, const float* __restrict__ wsp,
    const float* __restrict__ wse, const int* __restrict__ wsid,
    float* __restrict__ out, int n, int nblk)
{
    __shared__ float sred[256];
    __shared__ int bounds[2];
    const int g = blockIdx.x;
    const int d = threadIdx.x;

    float p = 0.f;
    for (int i = d; i < nblk; i += 256) p += wse[i];
    sred[d] = p;
    __syncthreads();
    for (int s = 128; s; s >>= 1) {
        if (d < s) sred[d] += sred[d + s];
        __syncthreads();
    }
    const float S = sred[0];

    if (d < 2) {
        int v = g + d;
        int lo = 0, hi = n;
        while (lo < hi) { int mid = (lo + hi) >> 1; if (batch[mid] < v) lo = mid + 1; else hi = mid; }
        bounds[d] = lo;
    }
    __syncthreads();

    const int st = bounds[0], en = bounds[1];
    float acc = 0.f;
    if (st < en) {
        for (int bb = st >> 7; bb <= (en - 1) >> 7; ++bb) {
            int slot = (wsid[bb] == g) ? 0 : 1;
            acc += wsp[(size_t)bb * 512 + slot * 256 + d];
        }
    }
    out[g * 256 + d] = acc / S;
}

// ---------------------------------------------------------------------------
extern "C" void kernel_launch(void* const* d_in, const int* in_sizes, int n_in,
                              void* d_out, int out_size, void* d_ws, size_t ws_size,
                              hipStream_t stream)
{
    const float* x     = (const float*)d_in[0];
    const int*   batch = (const int*)d_in[1];
    const float* w1    = (const float*)d_in[2];
    const float* b1    = (const float*)d_in[3];
    const float* w2    = (const float*)d_in[4];
    const float* b2    = (const float*)d_in[5];
    float* out = (float*)d_out;

    const int n    = in_sizes[1];                 // 200000
    const int nblk = (n + TILE - 1) / TILE;       // 1563

    // ws layout: w1f fragment-major bf16 (64KB) | wsp | wse | wsid
    ushort* w1f = (ushort*)d_ws;
    float*  wsp = (float*)((char*)d_ws + (size_t)DIM * HID * sizeof(ushort));
    float*  wse = wsp + (size_t)nblk * 512;
    int*    wsid = (int*)(wse + nblk);

    k_prep<<<dim3(DIM * HID / 256), dim3(256), 0, stream>>>(w1, w1f);
    k_scores<<<dim3(nblk), dim3(256), 0, stream>>>(x, batch, w1f,
                                                   b1, w2, b2, wsp, wse, wsid, n);
    k_combine<<<dim3(NGRAPHS), dim3(256), 0, stream>>>(batch, wsp, wse, wsid,
                                                       out, n, nblk);
}

// Round 12
// 84.386 us; speedup vs baseline: 7.3256x; 1.0258x over previous
//
#include <hip/hip_runtime.h>

#define NGRAPHS 256
#define DIM     256   // K (input dim)
#define HID     128   // N (hidden dim)
#define TILE    64    // rows per block (33 KB LDS -> 4 blocks/CU)

typedef __attribute__((ext_vector_type(8))) short bf16x8;
typedef __attribute__((ext_vector_type(4))) float f32x4;

__device__ __forceinline__ ushort f2bf_rne(float f) {
    unsigned u = __float_as_uint(f);
    unsigned r = u + 0x7fffu + ((u >> 16) & 1u);
    return (ushort)(r >> 16);
}
__device__ __forceinline__ float tanh_fast(float x) {
    float e = __expf(2.0f * x);
    return 1.0f - 2.0f * __builtin_amdgcn_rcpf(1.0f + e);
}
// pack two fp32 -> u32 holding 2 bf16 (RNE), elem0 in low half
__device__ __forceinline__ unsigned pack2(float a, float b) {
    unsigned ua = __float_as_uint(a), ub = __float_as_uint(b);
    unsigned ra = ua + 0x7fffu + ((ua >> 16) & 1u);
    unsigned rb = ub + 0x7fffu + ((ub >> 16) & 1u);
    return (ra >> 16) | (rb & 0xffff0000u);
}

// ---------------------------------------------------------------------------
// Prep: w1 [256(k)][128(n)] fp32 -> fragment-major bf16 RNE:
//   w1f[(ks*8+nf)*512 + lane*8 + j], lane = lhi*16+llo,
//   element = w1[ks*32+lhi*8+j][nf*16+llo]     (64 KB total, L2-hot)
// ---------------------------------------------------------------------------
__global__ void k_prep(const float* __restrict__ w1, ushort* __restrict__ w1f)
{
    int idx = blockIdx.x * 256 + threadIdx.x;   // 0..32767, k-major
    int k  = idx >> 7, nn = idx & 127;
    int ks = k >> 5, lhi = (k >> 3) & 3, j = k & 7;
    int nf = nn >> 4, llo = nn & 15;
    int lane = lhi * 16 + llo;
    w1f[(ks * 8 + nf) * 512 + lane * 8 + j] = f2bf_rne(w1[idx]);
}

// ---------------------------------------------------------------------------
// Main: stage 64x256 x tile ONCE as bf16 (32KB XOR-swizzled LDS). Barrier-
// free MFMA k-loop (A from LDS, B global->reg prefetched from L2-hot w1f).
// Epilogue: tanh, @w2, exp. Phase B reads the SAME LDS tile. Deterministic.
// ---------------------------------------------------------------------------
__global__ __launch_bounds__(256, 4) void k_scores(
    const float* __restrict__ x, const int* __restrict__ batch,
    const ushort* __restrict__ w1f,
    const float* __restrict__ b1, const float* __restrict__ w2,
    const float* __restrict__ b2,
    float* __restrict__ wsp, float* __restrict__ wse, int* __restrict__ wsid,
    int n)
{
    // x tile, bf16, row stride 512 B, 16B chunks XOR-swizzled by row&7
    __shared__ __align__(16) unsigned char xs[TILE * 512];   // 32 KB
    __shared__ float evals[TILE];
    __shared__ int   gid[TILE];
    __shared__ int   rtrans_s;
    __shared__ float ep[4];

    const int t    = threadIdx.x;
    const int b    = blockIdx.x;
    const int r0   = b * TILE;
    const int wid  = t >> 6;
    const int lane = t & 63;
    const int lhi  = lane >> 4;
    const int llo  = lane & 15;

    if (t < TILE) {
        int r = r0 + t;
        gid[t] = batch[r < n ? r : (n - 1)];
    }
    if (t == 0) rtrans_s = TILE;
    __syncthreads();
    // <=1 graph boundary per 64-row tile (min graph size ~650 >> 64)
    if (t >= 1 && t < TILE && gid[t] != gid[0] && gid[t - 1] == gid[0])
        rtrans_s = t;

    // ---- stage x tile: thread = quarter-row (64 floats), cvt->swizzled LDS ----
    const int rt = t >> 2, h = t & 3, rq = rt & 7;
    int xrow = r0 + rt; if (xrow >= n) xrow = n - 1;
    const float* xp  = x + (size_t)xrow * DIM + h * 64;
    unsigned char* xwp = xs + rt * 512;

    {
        float4 va[8], vb[8];
#pragma unroll
        for (int i = 0; i < 8; ++i) va[i] = *(const float4*)(xp + i * 4);
#pragma unroll
        for (int i = 0; i < 8; ++i) vb[i] = *(const float4*)(xp + 32 + i * 4);
#pragma unroll
        for (int w = 0; w < 4; ++w) {
            uint4 W;
            W.x = pack2(va[2 * w].x,     va[2 * w].y);
            W.y = pack2(va[2 * w].z,     va[2 * w].w);
            W.z = pack2(va[2 * w + 1].x, va[2 * w + 1].y);
            W.w = pack2(va[2 * w + 1].z, va[2 * w + 1].w);
            *(uint4*)(xwp + (((h * 8 + w) ^ rq) << 4)) = W;
        }
#pragma unroll
        for (int w = 0; w < 4; ++w) {
            uint4 W;
            W.x = pack2(vb[2 * w].x,     vb[2 * w].y);
            W.y = pack2(vb[2 * w].z,     vb[2 * w].w);
            W.z = pack2(vb[2 * w + 1].x, vb[2 * w + 1].y);
            W.w = pack2(vb[2 * w + 1].z, vb[2 * w + 1].w);
            *(uint4*)(xwp + (((h * 8 + 4 + w) ^ rq) << 4)) = W;
        }
    }
    __syncthreads();   // tile + gid + rtrans visible; xs immutable hereafter

    // ---- barrier-free k-loop: A from LDS, B global->reg (1-step prefetch) ----
    f32x4 acc[8];
#pragma unroll
    for (int j = 0; j < 8; ++j) acc[j] = (f32x4){0.f, 0.f, 0.f, 0.f};

    const int ra = wid * 16 + llo;
    const int q0 = ra & 7;
#define AADDR(KS) ((const bf16x8*)(xs + ra * 512 + (((((KS) * 4) + lhi) ^ q0) << 4)))
    const ushort* bp = w1f + lane * 8;

    bf16x8 aC = *AADDR(0);
    bf16x8 bC[8], bN[8];
#pragma unroll
    for (int nf = 0; nf < 8; ++nf) bC[nf] = *(const bf16x8*)(bp + nf * 512);

    bf16x8 aN;
#pragma unroll
    for (int ks = 0; ks < 8; ++ks) {
        if (ks < 7) {
            aN = *AADDR(ks + 1);
#pragma unroll
            for (int nf = 0; nf < 8; ++nf)
                bN[nf] = *(const bf16x8*)(bp + (ks + 1) * 4096 + nf * 512);
        }
        __builtin_amdgcn_sched_barrier(0);   // issue prefetch before MFMAs
#pragma unroll
        for (int nf = 0; nf < 8; ++nf)
            acc[nf] = __builtin_amdgcn_mfma_f32_16x16x32_bf16(aC, bC[nf], acc[nf], 0, 0, 0);
        __builtin_amdgcn_sched_barrier(0);
        if (ks < 7) {
            aC = aN;
#pragma unroll
            for (int nf = 0; nf < 8; ++nf) bC[nf] = bN[nf];
        }
    }
#undef AADDR

    // ---- epilogue: tanh + dot(w2); C layout: col=llo+16nf, row=lhi*4+rg ----
    float b2v = b2[0];
    float b1v[8], w2v[8];
#pragma unroll
    for (int nf = 0; nf < 8; ++nf) {
        b1v[nf] = b1[nf * 16 + llo];
        w2v[nf] = w2[nf * 16 + llo];
    }
    float sc[4];
#pragma unroll
    for (int rg = 0; rg < 4; ++rg) {
        float p = 0.f;
#pragma unroll
        for (int nf = 0; nf < 8; ++nf)
            p += tanh_fast(acc[nf][rg] + b1v[nf]) * w2v[nf];
        sc[rg] = p;
    }
#pragma unroll
    for (int off = 1; off < 16; off <<= 1)
#pragma unroll
        for (int q = 0; q < 4; ++q) sc[q] += __shfl_xor(sc[q], off, 64);

    if (llo == 0) {
#pragma unroll
        for (int rg = 0; rg < 4; ++rg) {
            int row = wid * 16 + lhi * 4 + rg;
            float s = sc[rg] + b2v;
            evals[row] = (r0 + row < n) ? __expf(s) : 0.f;
        }
    }
    __syncthreads();   // evals visible block-wide

    // ---- phase B: weighted per-graph column sums FROM LDS (thread = col t) ----
    {
        const int rtr  = rtrans_s;
        const int c    = t >> 3;            // 16B chunk of this column
        const int woff = (2 * t) & 15;      // byte offset within chunk
        float a0 = 0.f, a1 = 0.f;
#pragma unroll 8
        for (int r = 0; r < TILE; ++r) {
            float e = evals[r];
            ushort v = *(const ushort*)(xs + r * 512 + ((c ^ (r & 7)) << 4) + woff);
            float xv = __uint_as_float(((unsigned)v) << 16);
            if (r < rtr) a0 = fmaf(e, xv, a0);
            else         a1 = fmaf(e, xv, a1);
        }
        wsp[(size_t)b * 512 + t]       = a0;
        wsp[(size_t)b * 512 + 256 + t] = a1;
        if (t == 0) wsid[b] = gid[0];
    }

    // ---- block exp-sum (deterministic) ----
    float rsum = (t < TILE) ? evals[t] : 0.f;
#pragma unroll
    for (int off = 32; off; off >>= 1) rsum += __shfl_down(rsum, off, 64);
    if ((t & 63) == 0) ep[t >> 6] = rsum;
    __syncthreads();
    if (t == 0) wse[b] = ep[0] + ep[1] + ep[2] + ep[3];
}

// ---------------------------------------------------------------------------
// Combine: one block per graph
// ---------------------------------------------------------------------------
__global__ __launch_bounds__(256) void k_combine(
    const int* __restrict__ batch, const float* __restrict__ wsp,
    const float* __restrict__ wse, const int* __restrict__ wsid,
    float* __restrict__ out, int n, int nblk)
{
    __shared__ float sred[256];
    __shared__ int bounds[2];
    const int g = blockIdx.x;
    const int d = threadIdx.x;

    float p = 0.f;
    for (int i = d; i < nblk; i += 256) p += wse[i];
    sred[d] = p;
    __syncthreads();
    for (int s = 128; s; s >>= 1) {
        if (d < s) sred[d] += sred[d + s];
        __syncthreads();
    }
    const float S = sred[0];

    if (d < 2) {
        int v = g + d;
        int lo = 0, hi = n;
        while (lo < hi) { int mid = (lo + hi) >> 1; if (batch[mid] < v) lo = mid + 1; else hi = mid; }
        bounds[d] = lo;
    }
    __syncthreads();

    const int st = bounds[0], en = bounds[1];
    float acc = 0.f;
    if (st < en) {
        for (int bb = st >> 6; bb <= (en - 1) >> 6; ++bb) {   // TILE=64
            int slot = (wsid[bb] == g) ? 0 : 1;
            acc += wsp[(size_t)bb * 512 + slot * 256 + d];
        }
    }
    out[g * 256 + d] = acc / S;
}

// ---------------------------------------------------------------------------
extern "C" void kernel_launch(void* const* d_in, const int* in_sizes, int n_in,
                              void* d_out, int out_size, void* d_ws, size_t ws_size,
                              hipStream_t stream)
{
    const float* x     = (const float*)d_in[0];
    const int*   batch = (const int*)d_in[1];
    const float* w1    = (const float*)d_in[2];
    const float* b1    = (const float*)d_in[3];
    const float* w2    = (const float*)d_in[4];
    const float* b2    = (const float*)d_in[5];
    float* out = (float*)d_out;

    const int n    = in_sizes[1];                 // 200000
    const int nblk = (n + TILE - 1) / TILE;       // 3125

    // ws layout: w1f fragment-major bf16 (64KB) | wsp | wse | wsid
    ushort* w1f = (ushort*)d_ws;
    float*  wsp = (float*)((char*)d_ws + (size_t)DIM * HID * sizeof(ushort));
    float*  wse = wsp + (size_t)nblk * 512;
    int*    wsid = (int*)(wse + nblk);

    k_prep<<<dim3(DIM * HID / 256), dim3(256), 0, stream>>>(w1, w1f);
    k_scores<<<dim3(nblk), dim3(256), 0, stream>>>(x, batch, w1f,
                                                   b1, w2, b2, wsp, wse, wsid, n);
    k_combine<<<dim3(NGRAPHS), dim3(256), 0, stream>>>(batch, wsp, wse, wsid,
                                                       out, n, nblk);
}

// Round 13
// 81.191 us; speedup vs baseline: 7.6139x; 1.0393x over previous
//
#include <hip/hip_runtime.h>

#define NGRAPHS 256
#define DIM     256   // K (input dim)
#define HID     128   // N (hidden dim)
#define TILE    128   // rows per block

typedef __attribute__((ext_vector_type(8))) short bf16x8;
typedef __attribute__((ext_vector_type(4))) float f32x4;

__device__ __forceinline__ ushort f2bf_rne(float f) {
    unsigned u = __float_as_uint(f);
    unsigned r = u + 0x7fffu + ((u >> 16) & 1u);
    return (ushort)(r >> 16);
}
__device__ __forceinline__ float tanh_fast(float x) {
    float e = __expf(2.0f * x);
    return 1.0f - 2.0f * __builtin_amdgcn_rcpf(1.0f + e);
}
// pack two fp32 -> u32 holding 2 bf16 (RNE), elem0 in low half
__device__ __forceinline__ unsigned pack2(float a, float b) {
    unsigned ua = __float_as_uint(a), ub = __float_as_uint(b);
    unsigned ra = ua + 0x7fffu + ((ua >> 16) & 1u);
    unsigned rb = ub + 0x7fffu + ((ub >> 16) & 1u);
    return (ra >> 16) | (rb & 0xffff0000u);
}
__device__ __forceinline__ bf16x8 cvt8h(float4 v0, float4 v1) {
    union { unsigned w[4]; bf16x8 v; } H;
    H.w[0] = pack2(v0.x, v0.y);
    H.w[1] = pack2(v0.z, v0.w);
    H.w[2] = pack2(v1.x, v1.y);
    H.w[3] = pack2(v1.z, v1.w);
    return H.v;
}
// fire-and-forget global->LDS DMA, 16B per lane; lds ptr must be wave-uniform
__device__ __forceinline__ void glds16(const void* g, void* l) {
    __builtin_amdgcn_global_load_lds(
        (const __attribute__((address_space(1))) unsigned int*)g,
        (__attribute__((address_space(3))) unsigned int*)l, 16, 0, 0);
}

// ---------------------------------------------------------------------------
// Prep: w1 [256(k)][128(n)] fp32 -> fragment-major bf16 RNE:
//   w1f[(ks*8+nf)*512 + lane*8 + j], lane = lhi*16+llo,
//   element = w1[ks*32+lhi*8+j][nf*16+llo]     (64 KB total, L2-hot)
// ---------------------------------------------------------------------------
__global__ void k_prep(const float* __restrict__ w1, ushort* __restrict__ w1f)
{
    int idx = blockIdx.x * 256 + threadIdx.x;   // 0..32767, k-major
    int k  = idx >> 7, nn = idx & 127;
    int ks = k >> 5, lhi = (k >> 3) & 3, j = k & 7;
    int nf = nn >> 4, llo = nn & 15;
    int lane = lhi * 16 + llo;
    w1f[(ks * 8 + nf) * 512 + lane * 8 + j] = f2bf_rne(w1[idx]);
}

// ---------------------------------------------------------------------------
// Main: B staged ONCE into LDS (64 KB); A global->reg with 2-step prefetch;
// barrier-free MFMA k-loop (B from LDS). Epilogue: tanh, @w2, exp, with
// phase-B batch-0 loads issued EARLY (latency hides under epilogue).
// Phase B: fp32 global re-read, per-graph column partials. Deterministic.
// ---------------------------------------------------------------------------
__global__ __launch_bounds__(256, 2) void k_scores(
    const float* __restrict__ x, const int* __restrict__ batch,
    const ushort* __restrict__ w1f,
    const float* __restrict__ b1, const float* __restrict__ w2,
    const float* __restrict__ b2,
    float* __restrict__ wsp, float* __restrict__ wse, int* __restrict__ wsid,
    int n)
{
    __shared__ __align__(16) ushort bs[DIM * HID];   // 64 KB B copy
    __shared__ float evals[TILE];
    __shared__ int   gid[TILE];
    __shared__ float ep[4];
    float (*sred)[2][DIM] = (float(*)[2][DIM])&bs[0];   // alias (bs dead post-loop)

    const int t    = threadIdx.x;
    const int b    = blockIdx.x;
    const int r0   = b * TILE;
    const int wid  = t >> 6;
    const int lane = t & 63;
    const int lhi  = lane >> 4;
    const int llo  = lane & 15;

    if (t < TILE) {
        int r = r0 + t;
        gid[t] = batch[r < n ? r : (n - 1)];
    }

    // A-fragment rows for this lane (mf=0,1)
    int row0 = r0 + wid * 32 + llo;
    int row1 = row0 + 16;
    if (row0 >= n) row0 = n - 1;
    if (row1 >= n) row1 = n - 1;
    const float* xr0 = x + (size_t)row0 * DIM + lhi * 8;
    const float* xr1 = x + (size_t)row1 * DIM + lhi * 8;

    // ---- stage B: 16 glds16/thread, linear fragment-major ----
#pragma unroll
    for (int i = 0; i < 16; ++i)
        glds16(w1f + (size_t)(i * 256 + t) * 8,
               (unsigned char*)bs + (i * 256 + wid * 64) * 16);
    __builtin_amdgcn_sched_barrier(0);

    // ---- A prologue: 2 steps in flight ----
    float4 pA[2][4];
    pA[0][0] = *(const float4*)(xr0);      pA[0][1] = *(const float4*)(xr0 + 4);
    pA[0][2] = *(const float4*)(xr1);      pA[0][3] = *(const float4*)(xr1 + 4);
    pA[1][0] = *(const float4*)(xr0 + 32); pA[1][1] = *(const float4*)(xr0 + 36);
    pA[1][2] = *(const float4*)(xr1 + 32); pA[1][3] = *(const float4*)(xr1 + 36);
    __builtin_amdgcn_sched_barrier(0);
    asm volatile("s_waitcnt vmcnt(8)" ::: "memory");   // 16 glds16 done; A in flight
    __builtin_amdgcn_sched_barrier(0);
    __builtin_amdgcn_s_barrier();                      // B visible block-wide
    __builtin_amdgcn_sched_barrier(0);

    f32x4 acc[2][8];
#pragma unroll
    for (int i = 0; i < 2; ++i)
#pragma unroll
        for (int j = 0; j < 8; ++j) acc[i][j] = (f32x4){0.f, 0.f, 0.f, 0.f};

    // ---- barrier-free k-loop: A regs (compiler-tracked waits), B from LDS ----
#pragma unroll
    for (int ks = 0; ks < 8; ++ks) {
        const int cur = ks & 1;
        bf16x8 ah0 = cvt8h(pA[cur][0], pA[cur][1]);
        bf16x8 ah1 = cvt8h(pA[cur][2], pA[cur][3]);
        if (ks + 2 < 8) {   // reuse bank after consumption; static under unroll
            pA[cur][0] = *(const float4*)(xr0 + (ks + 2) * 32);
            pA[cur][1] = *(const float4*)(xr0 + (ks + 2) * 32 + 4);
            pA[cur][2] = *(const float4*)(xr1 + (ks + 2) * 32);
            pA[cur][3] = *(const float4*)(xr1 + (ks + 2) * 32 + 4);
        }
        __builtin_amdgcn_sched_barrier(0);
#pragma unroll
        for (int nf = 0; nf < 8; ++nf) {
            bf16x8 bh = *(const bf16x8*)&bs[ks * 4096 + nf * 512 + lane * 8];
            acc[0][nf] = __builtin_amdgcn_mfma_f32_16x16x32_bf16(ah0, bh, acc[0][nf], 0, 0, 0);
            acc[1][nf] = __builtin_amdgcn_mfma_f32_16x16x32_bf16(ah1, bh, acc[1][nf], 0, 0, 0);
        }
    }

    // ---- T14: issue phase-B batch 0 BEFORE epilogue (hides under tanh) ----
    float4 xv0[16];
#pragma unroll
    for (int j = 0; j < 16; ++j) {
        int rsrc = r0 + wid * 32 + j;
        if (rsrc >= n) rsrc = n - 1;
        xv0[j] = *(const float4*)(x + (size_t)rsrc * DIM + lane * 4);
    }
    __builtin_amdgcn_sched_barrier(0);

    // ---- epilogue: tanh + dot(w2); C layout: col=llo+16nf, row=lhi*4+rg ----
    float b2v = b2[0];
    float b1v[8], w2v[8];
#pragma unroll
    for (int nf = 0; nf < 8; ++nf) {
        b1v[nf] = b1[nf * 16 + llo];
        w2v[nf] = w2[nf * 16 + llo];
    }
    float sc[8];
#pragma unroll
    for (int mf = 0; mf < 2; ++mf)
#pragma unroll
        for (int rg = 0; rg < 4; ++rg) {
            float p = 0.f;
#pragma unroll
            for (int nf = 0; nf < 8; ++nf)
                p += tanh_fast(acc[mf][nf][rg] + b1v[nf]) * w2v[nf];
            sc[mf * 4 + rg] = p;
        }
#pragma unroll
    for (int off = 1; off < 16; off <<= 1)
#pragma unroll
        for (int q = 0; q < 8; ++q) sc[q] += __shfl_xor(sc[q], off, 64);

    if (llo == 0) {
#pragma unroll
        for (int mf = 0; mf < 2; ++mf)
#pragma unroll
            for (int rg = 0; rg < 4; ++rg) {
                int row = wid * 32 + mf * 16 + lhi * 4 + rg;
                float s = sc[mf * 4 + rg] + b2v;
                evals[row] = (r0 + row < n) ? __expf(s) : 0.f;
            }
    }
    __syncthreads();   // evals visible; bs dead -> sred alias safe

    // ---- phase B: issue batch 1, then accumulate batch 0, then batch 1 ----
    {
        float4 xv1[16];
#pragma unroll
        for (int j = 0; j < 16; ++j) {
            int rsrc = r0 + wid * 32 + 16 + j;
            if (rsrc >= n) rsrc = n - 1;
            xv1[j] = *(const float4*)(x + (size_t)rsrc * DIM + lane * 4);
        }
        __builtin_amdgcn_sched_barrier(0);

        const int g0 = gid[0];
        float4 a0 = {0.f, 0.f, 0.f, 0.f}, a1 = {0.f, 0.f, 0.f, 0.f};
#pragma unroll
        for (int j = 0; j < 16; ++j) {
            int row = wid * 32 + j;
            float e = evals[row];
            if (gid[row] != g0) {
                a1.x = fmaf(e, xv0[j].x, a1.x); a1.y = fmaf(e, xv0[j].y, a1.y);
                a1.z = fmaf(e, xv0[j].z, a1.z); a1.w = fmaf(e, xv0[j].w, a1.w);
            } else {
                a0.x = fmaf(e, xv0[j].x, a0.x); a0.y = fmaf(e, xv0[j].y, a0.y);
                a0.z = fmaf(e, xv0[j].z, a0.z); a0.w = fmaf(e, xv0[j].w, a0.w);
            }
        }
#pragma unroll
        for (int j = 0; j < 16; ++j) {
            int row = wid * 32 + 16 + j;
            float e = evals[row];
            if (gid[row] != g0) {
                a1.x = fmaf(e, xv1[j].x, a1.x); a1.y = fmaf(e, xv1[j].y, a1.y);
                a1.z = fmaf(e, xv1[j].z, a1.z); a1.w = fmaf(e, xv1[j].w, a1.w);
            } else {
                a0.x = fmaf(e, xv1[j].x, a0.x); a0.y = fmaf(e, xv1[j].y, a0.y);
                a0.z = fmaf(e, xv1[j].z, a0.z); a0.w = fmaf(e, xv1[j].w, a0.w);
            }
        }
        *(float4*)&sred[wid][0][lane * 4] = a0;
        *(float4*)&sred[wid][1][lane * 4] = a1;
    }
    __syncthreads();
    {
        float s0 = sred[0][0][t] + sred[1][0][t] + sred[2][0][t] + sred[3][0][t];
        float s1 = sred[0][1][t] + sred[1][1][t] + sred[2][1][t] + sred[3][1][t];
        wsp[(size_t)b * 512 + t]       = s0;
        wsp[(size_t)b * 512 + 256 + t] = s1;
        if (t == 0) wsid[b] = gid[0];
    }

    // ---- block exp-sum (deterministic) ----
    float rsum = (t < TILE) ? evals[t] : 0.f;
#pragma unroll
    for (int off = 32; off; off >>= 1) rsum += __shfl_down(rsum, off, 64);
    if ((t & 63) == 0) ep[t >> 6] = rsum;
    __syncthreads();
    if (t == 0) wse[b] = ep[0] + ep[1];
}

// ---------------------------------------------------------------------------
// Combine: one block per graph
// ---------------------------------------------------------------------------
__global__ __launch_bounds__(256) void k_combine(
    const int* __restrict__ batch, const float* __restrict__ wsp,
    const float* __restrict__ wse, const int* __restrict__ wsid,
    float* __restrict__ out, int n, int nblk)
{
    __shared__ float sred[256];
    __shared__ int bounds[2];
    const int g = blockIdx.x;
    const int d = threadIdx.x;

    float p = 0.f;
    for (int i = d; i < nblk; i += 256) p += wse[i];
    sred[d] = p;
    __syncthreads();
    for (int s = 128; s; s >>= 1) {
        if (d < s) sred[d] += sred[d + s];
        __syncthreads();
    }
    const float S = sred[0];

    if (d < 2) {
        int v = g + d;
        int lo = 0, hi = n;
        while (lo < hi) { int mid = (lo + hi) >> 1; if (batch[mid] < v) lo = mid + 1; else hi = mid; }
        bounds[d] = lo;
    }
    __syncthreads();

    const int st = bounds[0], en = bounds[1];
    float acc = 0.f;
    if (st < en) {
        for (int bb = st >> 7; bb <= (en - 1) >> 7; ++bb) {   // TILE=128
            int slot = (wsid[bb] == g) ? 0 : 1;
            acc += wsp[(size_t)bb * 512 + slot * 256 + d];
        }
    }
    out[g * 256 + d] = acc / S;
}

// ---------------------------------------------------------------------------
extern "C" void kernel_launch(void* const* d_in, const int* in_sizes, int n_in,
                              void* d_out, int out_size, void* d_ws, size_t ws_size,
                              hipStream_t stream)
{
    const float* x     = (const float*)d_in[0];
    const int*   batch = (const int*)d_in[1];
    const float* w1    = (const float*)d_in[2];
    const float* b1    = (const float*)d_in[3];
    const float* w2    = (const float*)d_in[4];
    const float* b2    = (const float*)d_in[5];
    float* out = (float*)d_out;

    const int n    = in_sizes[1];                 // 200000
    const int nblk = (n + TILE - 1) / TILE;       // 1563

    // ws layout: w1f fragment-major bf16 (64KB) | wsp | wse | wsid
    ushort* w1f = (ushort*)d_ws;
    float*  wsp = (float*)((char*)d_ws + (size_t)DIM * HID * sizeof(ushort));
    float*  wse = wsp + (size_t)nblk * 512;
    int*    wsid = (int*)(wse + nblk);

    k_prep<<<dim3(DIM * HID / 256), dim3(256), 0, stream>>>(w1, w1f);
    k_scores<<<dim3(nblk), dim3(256), 0, stream>>>(x, batch, w1f,
                                                   b1, w2, b2, wsp, wse, wsid, n);
    k_combine<<<dim3(NGRAPHS), dim3(256), 0, stream>>>(batch, wsp, wse, wsid,
                                                       out, n, nblk);
}

// Round 14
// 80.164 us; speedup vs baseline: 7.7115x; 1.0128x over previous
//
#include <hip/hip_runtime.h>

#define NGRAPHS 256
#define DIM     256   // K (input dim)
#define HID     128   // N (hidden dim)
#define TILE    128   // rows per tile
#define NPERS   512   // persistent blocks (2 per CU)

typedef __attribute__((ext_vector_type(8))) short bf16x8;
typedef __attribute__((ext_vector_type(4))) float f32x4;

__device__ __forceinline__ ushort f2bf_rne(float f) {
    unsigned u = __float_as_uint(f);
    unsigned r = u + 0x7fffu + ((u >> 16) & 1u);
    return (ushort)(r >> 16);
}
__device__ __forceinline__ float tanh_fast(float x) {
    float e = __expf(2.0f * x);
    return 1.0f - 2.0f * __builtin_amdgcn_rcpf(1.0f + e);
}
// pack two fp32 -> u32 holding 2 bf16 (RNE), elem0 in low half
__device__ __forceinline__ unsigned pack2(float a, float b) {
    unsigned ua = __float_as_uint(a), ub = __float_as_uint(b);
    unsigned ra = ua + 0x7fffu + ((ua >> 16) & 1u);
    unsigned rb = ub + 0x7fffu + ((ub >> 16) & 1u);
    return (ra >> 16) | (rb & 0xffff0000u);
}
__device__ __forceinline__ bf16x8 cvt8h(float4 v0, float4 v1) {
    union { unsigned w[4]; bf16x8 v; } H;
    H.w[0] = pack2(v0.x, v0.y);
    H.w[1] = pack2(v0.z, v0.w);
    H.w[2] = pack2(v1.x, v1.y);
    H.w[3] = pack2(v1.z, v1.w);
    return H.v;
}
// fire-and-forget global->LDS DMA, 16B per lane; lds ptr must be wave-uniform
__device__ __forceinline__ void glds16(const void* g, void* l) {
    __builtin_amdgcn_global_load_lds(
        (const __attribute__((address_space(1))) unsigned int*)g,
        (__attribute__((address_space(3))) unsigned int*)l, 16, 0, 0);
}

// ---------------------------------------------------------------------------
// Prep: w1 [256(k)][128(n)] fp32 -> fragment-major bf16 RNE:
//   w1f[(ks*8+nf)*512 + lane*8 + j], lane = lhi*16+llo,
//   element = w1[ks*32+lhi*8+j][nf*16+llo]     (64 KB total, L2-hot)
// ---------------------------------------------------------------------------
__global__ void k_prep(const float* __restrict__ w1, ushort* __restrict__ w1f)
{
    int idx = blockIdx.x * 256 + threadIdx.x;   // 0..32767, k-major
    int k  = idx >> 7, nn = idx & 127;
    int ks = k >> 5, lhi = (k >> 3) & 3, j = k & 7;
    int nf = nn >> 4, llo = nn & 15;
    int lane = lhi * 16 + llo;
    w1f[(ks * 8 + nf) * 512 + lane * 8 + j] = f2bf_rne(w1[idx]);
}

// ---------------------------------------------------------------------------
// Main (persistent): B staged ONCE per block into LDS; grid-stride loop over
// tiles with the R13 inner structure: A global->reg 2-step prefetch,
// barrier-free MFMA k-loop, T14 early phase-B loads, fp32-exact phase B.
// Deterministic (fixed tile->block assignment, no atomics).
// ---------------------------------------------------------------------------
__global__ __launch_bounds__(256, 2) void k_scores(
    const float* __restrict__ x, const int* __restrict__ batch,
    const ushort* __restrict__ w1f,
    const float* __restrict__ b1, const float* __restrict__ w2,
    const float* __restrict__ b2,
    float* __restrict__ wsp, float* __restrict__ wse, int* __restrict__ wsid,
    int n, int nblk)
{
    __shared__ __align__(16) ushort bs[DIM * HID];   // 64 KB, live whole kernel
    __shared__ float sred[4][2][DIM];                // 8 KB
    __shared__ float evals[TILE];
    __shared__ int   gid[TILE];
    __shared__ float ep[4];

    const int t    = threadIdx.x;
    const int wid  = t >> 6;
    const int lane = t & 63;
    const int lhi  = lane >> 4;
    const int llo  = lane & 15;

    // ---- stage B once: 16 glds16/thread, linear fragment-major ----
#pragma unroll
    for (int i = 0; i < 16; ++i)
        glds16(w1f + (size_t)(i * 256 + t) * 8,
               (unsigned char*)bs + (i * 256 + wid * 64) * 16);
    asm volatile("s_waitcnt vmcnt(0)" ::: "memory");
    __builtin_amdgcn_s_barrier();      // B visible block-wide, forever

    float b2v = b2[0];
    float b1v[8], w2v[8];
#pragma unroll
    for (int nf = 0; nf < 8; ++nf) {
        b1v[nf] = b1[nf * 16 + llo];
        w2v[nf] = w2[nf * 16 + llo];
    }

    for (int tid = blockIdx.x; tid < nblk; tid += NPERS) {
        const int r0 = tid * TILE;

        if (t < TILE) {
            int r = r0 + t;
            gid[t] = batch[r < n ? r : (n - 1)];
        }

        // A-fragment rows for this lane (mf=0,1)
        int row0 = r0 + wid * 32 + llo;
        int row1 = row0 + 16;
        if (row0 >= n) row0 = n - 1;
        if (row1 >= n) row1 = n - 1;
        const float* xr0 = x + (size_t)row0 * DIM + lhi * 8;
        const float* xr1 = x + (size_t)row1 * DIM + lhi * 8;

        // ---- A prologue: 2 steps in flight ----
        float4 pA[2][4];
        pA[0][0] = *(const float4*)(xr0);      pA[0][1] = *(const float4*)(xr0 + 4);
        pA[0][2] = *(const float4*)(xr1);      pA[0][3] = *(const float4*)(xr1 + 4);
        pA[1][0] = *(const float4*)(xr0 + 32); pA[1][1] = *(const float4*)(xr0 + 36);
        pA[1][2] = *(const float4*)(xr1 + 32); pA[1][3] = *(const float4*)(xr1 + 36);
        __builtin_amdgcn_sched_barrier(0);

        f32x4 acc[2][8];
#pragma unroll
        for (int i = 0; i < 2; ++i)
#pragma unroll
            for (int j = 0; j < 8; ++j) acc[i][j] = (f32x4){0.f, 0.f, 0.f, 0.f};

        // ---- barrier-free k-loop: A regs (compiler waits), B from LDS ----
#pragma unroll
        for (int ks = 0; ks < 8; ++ks) {
            const int cur = ks & 1;
            bf16x8 ah0 = cvt8h(pA[cur][0], pA[cur][1]);
            bf16x8 ah1 = cvt8h(pA[cur][2], pA[cur][3]);
            if (ks + 2 < 8) {
                pA[cur][0] = *(const float4*)(xr0 + (ks + 2) * 32);
                pA[cur][1] = *(const float4*)(xr0 + (ks + 2) * 32 + 4);
                pA[cur][2] = *(const float4*)(xr1 + (ks + 2) * 32);
                pA[cur][3] = *(const float4*)(xr1 + (ks + 2) * 32 + 4);
            }
            __builtin_amdgcn_sched_barrier(0);
#pragma unroll
            for (int nf = 0; nf < 8; ++nf) {
                bf16x8 bh = *(const bf16x8*)&bs[ks * 4096 + nf * 512 + lane * 8];
                acc[0][nf] = __builtin_amdgcn_mfma_f32_16x16x32_bf16(ah0, bh, acc[0][nf], 0, 0, 0);
                acc[1][nf] = __builtin_amdgcn_mfma_f32_16x16x32_bf16(ah1, bh, acc[1][nf], 0, 0, 0);
            }
        }

        // ---- T14: issue phase-B batch 0 BEFORE epilogue ----
        float4 xv0[16];
#pragma unroll
        for (int j = 0; j < 16; ++j) {
            int rsrc = r0 + wid * 32 + j;
            if (rsrc >= n) rsrc = n - 1;
            xv0[j] = *(const float4*)(x + (size_t)rsrc * DIM + lane * 4);
        }
        __builtin_amdgcn_sched_barrier(0);

        // ---- epilogue: tanh + dot(w2); C: col=llo+16nf, row=lhi*4+rg ----
        float sc[8];
#pragma unroll
        for (int mf = 0; mf < 2; ++mf)
#pragma unroll
            for (int rg = 0; rg < 4; ++rg) {
                float p = 0.f;
#pragma unroll
                for (int nf = 0; nf < 8; ++nf)
                    p += tanh_fast(acc[mf][nf][rg] + b1v[nf]) * w2v[nf];
                sc[mf * 4 + rg] = p;
            }
#pragma unroll
        for (int off = 1; off < 16; off <<= 1)
#pragma unroll
            for (int q = 0; q < 8; ++q) sc[q] += __shfl_xor(sc[q], off, 64);

        if (llo == 0) {
#pragma unroll
            for (int mf = 0; mf < 2; ++mf)
#pragma unroll
                for (int rg = 0; rg < 4; ++rg) {
                    int row = wid * 32 + mf * 16 + lhi * 4 + rg;
                    float s = sc[mf * 4 + rg] + b2v;
                    evals[row] = (r0 + row < n) ? __expf(s) : 0.f;
                }
        }
        __syncthreads();   // #1: evals + gid visible

        // ---- phase B: issue batch 1, accumulate batch 0 then batch 1 ----
        {
            float4 xv1[16];
#pragma unroll
            for (int j = 0; j < 16; ++j) {
                int rsrc = r0 + wid * 32 + 16 + j;
                if (rsrc >= n) rsrc = n - 1;
                xv1[j] = *(const float4*)(x + (size_t)rsrc * DIM + lane * 4);
            }
            __builtin_amdgcn_sched_barrier(0);

            const int g0 = gid[0];
            float4 a0 = {0.f, 0.f, 0.f, 0.f}, a1 = {0.f, 0.f, 0.f, 0.f};
#pragma unroll
            for (int j = 0; j < 16; ++j) {
                int row = wid * 32 + j;
                float e = evals[row];
                if (gid[row] != g0) {
                    a1.x = fmaf(e, xv0[j].x, a1.x); a1.y = fmaf(e, xv0[j].y, a1.y);
                    a1.z = fmaf(e, xv0[j].z, a1.z); a1.w = fmaf(e, xv0[j].w, a1.w);
                } else {
                    a0.x = fmaf(e, xv0[j].x, a0.x); a0.y = fmaf(e, xv0[j].y, a0.y);
                    a0.z = fmaf(e, xv0[j].z, a0.z); a0.w = fmaf(e, xv0[j].w, a0.w);
                }
            }
#pragma unroll
            for (int j = 0; j < 16; ++j) {
                int row = wid * 32 + 16 + j;
                float e = evals[row];
                if (gid[row] != g0) {
                    a1.x = fmaf(e, xv1[j].x, a1.x); a1.y = fmaf(e, xv1[j].y, a1.y);
                    a1.z = fmaf(e, xv1[j].z, a1.z); a1.w = fmaf(e, xv1[j].w, a1.w);
                } else {
                    a0.x = fmaf(e, xv1[j].x, a0.x); a0.y = fmaf(e, xv1[j].y, a0.y);
                    a0.z = fmaf(e, xv1[j].z, a0.z); a0.w = fmaf(e, xv1[j].w, a0.w);
                }
            }
            *(float4*)&sred[wid][0][lane * 4] = a0;
            *(float4*)&sred[wid][1][lane * 4] = a1;
        }
        __syncthreads();   // #2: sred complete
        {
            float s0 = sred[0][0][t] + sred[1][0][t] + sred[2][0][t] + sred[3][0][t];
            float s1 = sred[0][1][t] + sred[1][1][t] + sred[2][1][t] + sred[3][1][t];
            wsp[(size_t)tid * 512 + t]       = s0;
            wsp[(size_t)tid * 512 + 256 + t] = s1;
            if (t == 0) wsid[tid] = gid[0];
        }

        // ---- block exp-sum (deterministic) ----
        float rsum = (t < TILE) ? evals[t] : 0.f;
#pragma unroll
        for (int off = 32; off; off >>= 1) rsum += __shfl_down(rsum, off, 64);
        if ((t & 63) == 0) ep[t >> 6] = rsum;
        __syncthreads();   // #3: ep complete; all tile-i shared reads done
        if (t == 0) wse[tid] = ep[0] + ep[1];
    }
}

// ---------------------------------------------------------------------------
// Combine: one block per graph
// ---------------------------------------------------------------------------
__global__ __launch_bounds__(256) void k_combine(
    const int* __restrict__ batch, const float* __restrict__ wsp,
    const float* __restrict__ wse, const int* __restrict__ wsid,
    float* __restrict__ out, int n, int nblk)
{
    __shared__ float sred[256];
    __shared__ int bounds[2];
    const int g = blockIdx.x;
    const int d = threadIdx.x;

    float p = 0.f;
    for (int i = d; i < nblk; i += 256) p += wse[i];
    sred[d] = p;
    __syncthreads();
    for (int s = 128; s; s >>= 1) {
        if (d < s) sred[d] += sred[d + s];
        __syncthreads();
    }
    const float S = sred[0];

    if (d < 2) {
        int v = g + d;
        int lo = 0, hi = n;
        while (lo < hi) { int mid = (lo + hi) >> 1; if (batch[mid] < v) lo = mid + 1; else hi = mid; }
        bounds[d] = lo;
    }
    __syncthreads();

    const int st = bounds[0], en = bounds[1];
    float acc = 0.f;
    if (st < en) {
        for (int bb = st >> 7; bb <= (en - 1) >> 7; ++bb) {   // TILE=128
            int slot = (wsid[bb] == g) ? 0 : 1;
            acc += wsp[(size_t)bb * 512 + slot * 256 + d];
        }
    }
    out[g * 256 + d] = acc / S;
}

// ---------------------------------------------------------------------------
extern "C" void kernel_launch(void* const* d_in, const int* in_sizes, int n_in,
                              void* d_out, int out_size, void* d_ws, size_t ws_size,
                              hipStream_t stream)
{
    const float* x     = (const float*)d_in[0];
    const int*   batch = (const int*)d_in[1];
    const float* w1    = (const float*)d_in[2];
    const float* b1    = (const float*)d_in[3];
    const float* w2    = (const float*)d_in[4];
    const float* b2    = (const float*)d_in[5];
    float* out = (float*)d_out;

    const int n    = in_sizes[1];                 // 200000
    const int nblk = (n + TILE - 1) / TILE;       // 1563

    // ws layout: w1f fragment-major bf16 (64KB) | wsp | wse | wsid
    ushort* w1f = (ushort*)d_ws;
    float*  wsp = (float*)((char*)d_ws + (size_t)DIM * HID * sizeof(ushort));
    float*  wse = wsp + (size_t)nblk * 512;
    int*    wsid = (int*)(wse + nblk);

    k_prep<<<dim3(DIM * HID / 256), dim3(256), 0, stream>>>(w1, w1f);
    k_scores<<<dim3(NPERS), dim3(256), 0, stream>>>(x, batch, w1f,
                                                    b1, w2, b2, wsp, wse, wsid,
                                                    n, nblk);
    k_combine<<<dim3(NGRAPHS), dim3(256), 0, stream>>>(batch, wsp, wse, wsid,
                                                       out, n, nblk);
}